// Round 1
// baseline (5129.726 us; speedup 1.0000x reference)
//
#include <hip/hip_runtime.h>
#include <hip/hip_bf16.h>
#include <math.h>

// Problem constants
#define Bb 4
#define Ls 1024
#define DHc 2048
#define Dh 128
#define HQc 16
#define HKc 4
#define Hc 16
#define Mrows 4096   // Bb*Ls

// ---------------------------------------------------------------------------
// Tiled fp32 GEMM: C[M,N] = A[M,K] @ B[K,N]; M=4096 fixed via gridDim.y*128.
// 128x128 tile, BK=8, 256 threads, 8x8 accum per thread.
// ---------------------------------------------------------------------------
__launch_bounds__(256)
__global__ void sgemm128(const float* __restrict__ A, const float* __restrict__ B,
                         float* __restrict__ C, int N, int K)
{
    __shared__ float As[8][132];
    __shared__ float Bs[8][132];
    const int tid = threadIdx.x;
    const int tx = tid & 15;        // N direction
    const int ty = tid >> 4;        // M direction
    const int row0 = blockIdx.y * 128;
    const int col0 = blockIdx.x * 128;

    const int arow = tid >> 1;
    const int acol = (tid & 1) << 2;
    const int brow = tid >> 5;
    const int bcol = (tid & 31) << 2;

    float acc[8][8];
#pragma unroll
    for (int i = 0; i < 8; i++)
#pragma unroll
        for (int j = 0; j < 8; j++) acc[i][j] = 0.f;

    const float* Ap = A + (size_t)(row0 + arow) * K + acol;
    const float* Bp = B + (size_t)brow * N + col0 + bcol;

    for (int k0 = 0; k0 < K; k0 += 8) {
        float4 av = *(const float4*)Ap;
        float4 bv = *(const float4*)Bp;
        __syncthreads();
        As[acol + 0][arow] = av.x;
        As[acol + 1][arow] = av.y;
        As[acol + 2][arow] = av.z;
        As[acol + 3][arow] = av.w;
        *(float4*)&Bs[brow][bcol] = bv;
        __syncthreads();
#pragma unroll
        for (int kk = 0; kk < 8; kk++) {
            float a[8], b[8];
            *(float4*)&a[0] = *(const float4*)&As[kk][ty * 8];
            *(float4*)&a[4] = *(const float4*)&As[kk][ty * 8 + 4];
            *(float4*)&b[0] = *(const float4*)&Bs[kk][tx * 8];
            *(float4*)&b[4] = *(const float4*)&Bs[kk][tx * 8 + 4];
#pragma unroll
            for (int i = 0; i < 8; i++)
#pragma unroll
                for (int j = 0; j < 8; j++) acc[i][j] += a[i] * b[j];
        }
        Ap += 8;
        Bp += (size_t)8 * N;
    }

    float* Cp = C + (size_t)(row0 + ty * 8) * N + col0 + tx * 8;
#pragma unroll
    for (int i = 0; i < 8; i++) {
        float4 c0 = make_float4(acc[i][0], acc[i][1], acc[i][2], acc[i][3]);
        float4 c1 = make_float4(acc[i][4], acc[i][5], acc[i][6], acc[i][7]);
        *(float4*)(Cp + (size_t)i * N) = c0;
        *(float4*)(Cp + (size_t)i * N + 4) = c1;
    }
}

// ---------------------------------------------------------------------------
// Causal depthwise conv (K=4) + SiLU + optional per-head l2norm (+scale).
// grid: Bb*Ls*NH blocks, 128 threads (one head-row of D=128 channels).
// pre: [B,L,NH*D], w: [NH*D,4], out: [B,L,NH*D]
// ---------------------------------------------------------------------------
__global__ void conv_silu_norm(const float* __restrict__ pre, const float* __restrict__ w,
                               float* __restrict__ out, int NH, int do_norm, float scale)
{
    __shared__ float red[2];
    const int idx = blockIdx.x;
    const int head = idx % NH;
    const int l = (idx / NH) % Ls;
    const int b = idx / (NH * Ls);
    const int C = NH * Dh;
    const int c = head * Dh + threadIdx.x;
    const float* base = pre + ((size_t)b * Ls + l) * C + c;
    const float4 wv = *(const float4*)(w + (size_t)c * 4);

    float v0 = (l >= 3) ? base[-3 * C] : 0.f;
    float v1 = (l >= 2) ? base[-2 * C] : 0.f;
    float v2 = (l >= 1) ? base[-1 * C] : 0.f;
    float v3 = base[0];
    float y = v0 * wv.x + v1 * wv.y + v2 * wv.z + v3 * wv.w;
    y = y / (1.f + expf(-y));   // SiLU

    if (do_norm) {
        float ss = y * y;
#pragma unroll
        for (int off = 32; off > 0; off >>= 1) ss += __shfl_xor(ss, off);
        if ((threadIdx.x & 63) == 0) red[threadIdx.x >> 6] = ss;
        __syncthreads();
        float tot = red[0] + red[1];
        y = y * rsqrtf(tot + 1e-6f) * scale;
    }
    out[((size_t)b * Ls + l) * C + c] = y;
}

// ---------------------------------------------------------------------------
// Small projections (N=16) with fused activations: beta=sigmoid(x@Wb),
// g = -exp(A_log)*softplus(x@Wgk + dt_bias). grid: 4096 rows, 64 threads.
// ---------------------------------------------------------------------------
__global__ void proj_small(const float* __restrict__ x, const float* __restrict__ Wb,
                           const float* __restrict__ Wgk, const float* __restrict__ A_log,
                           const float* __restrict__ dt_bias,
                           float* __restrict__ beta, float* __restrict__ g)
{
    const int row = blockIdx.x;
    const float* xr = x + (size_t)row * DHc;
    float accb[16], accg[16];
#pragma unroll
    for (int i = 0; i < 16; i++) { accb[i] = 0.f; accg[i] = 0.f; }

    for (int t = threadIdx.x; t < DHc; t += 64) {
        float xv = xr[t];
        const float* wb = Wb + (size_t)t * 16;
        const float* wg = Wgk + (size_t)t * 16;
#pragma unroll
        for (int hh = 0; hh < 16; hh++) {
            accb[hh] += xv * wb[hh];
            accg[hh] += xv * wg[hh];
        }
    }
#pragma unroll
    for (int hh = 0; hh < 16; hh++) {
        float vb = accb[hh], vg = accg[hh];
#pragma unroll
        for (int off = 32; off > 0; off >>= 1) {
            vb += __shfl_xor(vb, off);
            vg += __shfl_xor(vg, off);
        }
        if (threadIdx.x == 0) {
            beta[(size_t)row * 16 + hh] = 1.f / (1.f + expf(-vb));
            float z = vg + dt_bias[hh];
            float sp = (z > 20.f) ? z : log1pf(expf(z));
            g[(size_t)row * 16 + hh] = -expf(A_log[hh]) * sp;
        }
    }
}

// ---------------------------------------------------------------------------
// Gated delta-rule recurrence. State S[k][v] per (b,h) is column-parallel in v:
// grid = B*H*2 blocks (each block = 1 wave = 64 v-columns), thread owns one
// 128-deep k-column of state in VGPRs.
// ---------------------------------------------------------------------------
__launch_bounds__(64)
__global__ void gdn_recurrence(const float* __restrict__ qc, const float* __restrict__ kc,
                               const float* __restrict__ vc, const float* __restrict__ beta,
                               const float* __restrict__ g, float* __restrict__ o)
{
    const int tid = threadIdx.x;
    const int blk = blockIdx.x;
    const int half = blk & 1;
    const int h = (blk >> 1) & 15;
    const int b = blk >> 5;
    const int hk = h >> 2;              // GQA: 4 q-heads per kv-head
    const int col = (half << 6) + tid;  // v column this thread owns

    __shared__ float sk[128];
    __shared__ float sq[128];

    float s[128];
#pragma unroll
    for (int i = 0; i < 128; i++) s[i] = 0.f;

    const float* qrow = qc + ((size_t)b * Ls * Hc + h) * Dh;
    const float* krow = kc + ((size_t)b * Ls * HKc + hk) * Dh;
    const float* vrow = vc + ((size_t)b * Ls * HKc + hk) * Dh + col;
    const float* grow = g + (size_t)b * Ls * Hc + h;
    const float* brow = beta + (size_t)b * Ls * Hc + h;
    float* orow = o + ((size_t)b * Ls * Hc + h) * Dh + col;

    // prefetch t=0
    float pk0 = krow[tid], pk1 = krow[tid + 64];
    float pq0 = qrow[tid], pq1 = qrow[tid + 64];
    float pv = *vrow, pg = *grow, pb = *brow;

    for (int t = 0; t < Ls; ++t) {
        sk[tid] = pk0; sk[tid + 64] = pk1;
        sq[tid] = pq0; sq[tid + 64] = pq1;
        const float vt = pv, gt = pg, bt = pb;
        __syncthreads();
        if (t + 1 < Ls) {   // prefetch next step while computing
            qrow += Hc * Dh; krow += HKc * Dh; vrow += HKc * Dh; grow += Hc; brow += Hc;
            pk0 = krow[tid]; pk1 = krow[tid + 64];
            pq0 = qrow[tid]; pq1 = qrow[tid + 64];
            pv = *vrow; pg = *grow; pb = *brow;
        }
        const float eg = expf(gt);
        const float4* sk4 = (const float4*)sk;
        const float4* sq4 = (const float4*)sq;

        // pass 1: k . S_old (this thread's column)
        float acck = 0.f;
#pragma unroll
        for (int i = 0; i < 32; i++) {
            float4 kk = sk4[i];
            acck += kk.x * s[4 * i] + kk.y * s[4 * i + 1] + kk.z * s[4 * i + 2] + kk.w * s[4 * i + 3];
        }
        const float vres = vt - eg * acck;
        const float bv = bt * vres;

        // pass 2: state update + o = q . S_new
        float ov = 0.f;
#pragma unroll
        for (int i = 0; i < 32; i++) {
            float4 kk = sk4[i];
            float4 qq = sq4[i];
            float s0 = eg * s[4 * i]     + kk.x * bv; s[4 * i]     = s0; ov += qq.x * s0;
            float s1 = eg * s[4 * i + 1] + kk.y * bv; s[4 * i + 1] = s1; ov += qq.y * s1;
            float s2 = eg * s[4 * i + 2] + kk.z * bv; s[4 * i + 2] = s2; ov += qq.z * s2;
            float s3 = eg * s[4 * i + 3] + kk.w * bv; s[4 * i + 3] = s3; ov += qq.w * s3;
        }
        *orow = ov;
        orow += Hc * Dh;
        __syncthreads();
    }
}

// ---------------------------------------------------------------------------
// FusedRMSNormGated: o = o * rsqrt(mean(o^2)+eps) * w * silu(gate), in place.
// grid: B*L*H blocks, 64 threads (2 elems/thread of D=128).
// ---------------------------------------------------------------------------
__global__ void gated_rmsnorm(float* __restrict__ o, const float* __restrict__ gate,
                              const float* __restrict__ w)
{
    const size_t row = blockIdx.x;
    float* op = o + row * Dh;
    const float* gp = gate + row * Dh;
    const int t = threadIdx.x;
    float o0 = op[t], o1 = op[t + 64];
    float ss = o0 * o0 + o1 * o1;
#pragma unroll
    for (int off = 32; off > 0; off >>= 1) ss += __shfl_xor(ss, off);
    float r = rsqrtf(ss * (1.f / 128.f) + 1e-5f);
    float g0 = gp[t], g1 = gp[t + 64];
    float w0 = w[t], w1 = w[t + 64];
    op[t]      = o0 * r * w0 * (g0 / (1.f + expf(-g0)));
    op[t + 64] = o1 * r * w1 * (g1 / (1.f + expf(-g1)));
}

// ---------------------------------------------------------------------------
extern "C" void kernel_launch(void* const* d_in, const int* in_sizes, int n_in,
                              void* d_out, int out_size, void* d_ws, size_t ws_size,
                              hipStream_t stream)
{
    const float* x     = (const float*)d_in[0];
    const float* Wq    = (const float*)d_in[1];
    const float* Wk    = (const float*)d_in[2];
    const float* Wv    = (const float*)d_in[3];
    const float* Wb    = (const float*)d_in[4];
    const float* Wgk   = (const float*)d_in[5];
    const float* A_log = (const float*)d_in[6];
    const float* dtb   = (const float*)d_in[7];
    const float* cq    = (const float*)d_in[8];
    const float* ck    = (const float*)d_in[9];
    const float* cv    = (const float*)d_in[10];
    const float* Wg    = (const float*)d_in[11];
    const float* onw   = (const float*)d_in[12];
    const float* Wo    = (const float*)d_in[13];
    float* out = (float*)d_out;

    float* ws = (float*)d_ws;
    float* qc  = ws;                                  // [4096,2048]
    float* kcb = qc  + (size_t)Mrows * 2048;          // [4096,512]
    float* vcb = kcb + (size_t)Mrows * 512;           // [4096,512]
    float* bb  = vcb + (size_t)Mrows * 512;           // [4096,16]
    float* gb  = bb  + (size_t)Mrows * 16;            // [4096,16]
    float* ob  = gb  + (size_t)Mrows * 16;            // [4096,2048]
    size_t base = (size_t)Mrows * 2048 * 2 + (size_t)Mrows * 512 * 2 + (size_t)Mrows * 16 * 2;
    // scratch holds pre-activations then the gate; fall back to d_out if ws is tight
    float* scratch = (ws_size >= (base + (size_t)Mrows * 2048) * sizeof(float))
                         ? (ob + (size_t)Mrows * 2048)
                         : (float*)d_out;

    const float qscale = 0.08838834764831845f; // D^-0.5

    // q: project, conv+silu+l2norm(+scale)
    sgemm128<<<dim3(16, 32), 256, 0, stream>>>(x, Wq, scratch, 2048, 2048);
    conv_silu_norm<<<Bb * Ls * HQc, 128, 0, stream>>>(scratch, cq, qc, HQc, 1, qscale);
    // k
    sgemm128<<<dim3(4, 32), 256, 0, stream>>>(x, Wk, scratch, 512, 2048);
    conv_silu_norm<<<Bb * Ls * HKc, 128, 0, stream>>>(scratch, ck, kcb, HKc, 1, 1.0f);
    // v (no norm)
    sgemm128<<<dim3(4, 32), 256, 0, stream>>>(x, Wv, scratch, 512, 2048);
    conv_silu_norm<<<Bb * Ls * HKc, 128, 0, stream>>>(scratch, cv, vcb, HKc, 0, 1.0f);
    // beta / g scalars
    proj_small<<<Mrows, 64, 0, stream>>>(x, Wb, Wgk, A_log, dtb, bb, gb);
    // gate projection
    sgemm128<<<dim3(16, 32), 256, 0, stream>>>(x, Wg, scratch, 2048, 2048);
    // sequential gated delta-rule recurrence
    gdn_recurrence<<<Bb * Hc * 2, 64, 0, stream>>>(qc, kcb, vcb, bb, gb, ob);
    // gated rmsnorm (in place on ob), then output projection
    gated_rmsnorm<<<Bb * Ls * Hc, 64, 0, stream>>>(ob, scratch, onw);
    sgemm128<<<dim3(16, 32), 256, 0, stream>>>(ob, Wo, out, 2048, 2048);
}

// Round 2
// 1735.361 us; speedup vs baseline: 2.9560x; 2.9560x over previous
//
#include <hip/hip_runtime.h>
#include <hip/hip_bf16.h>
#include <math.h>

#define Bb 4
#define Ls 1024
#define DHc 2048
#define Dh 128
#define HQc 16
#define HKc 4
#define Hc 16
#define Mrows 4096   // Bb*Ls

typedef __attribute__((ext_vector_type(8))) short bf16x8;
typedef __attribute__((ext_vector_type(4))) float f32x4;

// ---------------------------------------------------------------------------
// fp32 -> bf16 elementwise convert (n % 4 == 0)
// ---------------------------------------------------------------------------
__global__ void f32_to_bf16(const float* __restrict__ in, __hip_bfloat16* __restrict__ out, int n)
{
    int i = (blockIdx.x * 256 + threadIdx.x) * 4;
    if (i >= n) return;
    float4 v = *(const float4*)(in + i);
    __hip_bfloat16 h[4];
    h[0] = __float2bfloat16(v.x); h[1] = __float2bfloat16(v.y);
    h[2] = __float2bfloat16(v.z); h[3] = __float2bfloat16(v.w);
    *(uint2*)(out + i) = *(uint2*)h;
}

// ---------------------------------------------------------------------------
// Transpose + convert: W fp32 [Krows, Ncols] -> BT bf16 [Ncols, Krows].
// 64x64 tile, 256 threads. Both dims must be multiples of 64 (they are).
// ---------------------------------------------------------------------------
__launch_bounds__(256)
__global__ void transpose_to_bf16(const float* __restrict__ W, __hip_bfloat16* __restrict__ BT,
                                  int Krows, int Ncols)
{
    __shared__ float tile[64][65];
    const int n0 = blockIdx.x * 64, k0 = blockIdx.y * 64;
    const int tx = threadIdx.x & 63, ty = threadIdx.x >> 6;
#pragma unroll
    for (int r = ty; r < 64; r += 4)
        tile[r][tx] = W[(size_t)(k0 + r) * Ncols + n0 + tx];
    __syncthreads();
#pragma unroll
    for (int r = ty; r < 64; r += 4)
        BT[(size_t)(n0 + r) * Krows + k0 + tx] = __float2bfloat16(tile[tx][r]);
}

// ---------------------------------------------------------------------------
// bf16 MFMA GEMM: C[M,N] = A[M,K] @ BT[N,K]^T.  A,BT bf16 row-major (K
// contiguous). 128x128 tile, BK=32, 256 threads = 4 waves (2x2 of 64x64),
// each wave 4x4 grid of 16x16x32 MFMA. C written fp32 or bf16.
// M = gridDim.y*128, N = gridDim.x*128, K % 32 == 0.
// ---------------------------------------------------------------------------
__launch_bounds__(256)
__global__ void gemm_bt_bf16(const __hip_bfloat16* __restrict__ A, const __hip_bfloat16* __restrict__ BT,
                             void* __restrict__ C, int N, int K, int c_bf16)
{
    // LDS tiles: 128 rows x 32 bf16, row stride 40 bf16 (=80B: 2-way bank spread, 16B aligned)
    __shared__ __align__(16) unsigned short As[128 * 40];
    __shared__ __align__(16) unsigned short Bs[128 * 40];
    const int tid = threadIdx.x;
    const int lane = tid & 63;
    const int wave = tid >> 6;
    const int wm = (wave >> 1) * 64, wn = (wave & 1) * 64;
    const int row0 = blockIdx.y * 128, col0 = blockIdx.x * 128;

    // staging: granule = 8 bf16 (16B); tile has 512 granules; thread does g0=tid, g1=tid+256
    const int g0 = tid, g1 = tid + 256;
    const __hip_bfloat16* Ap0 = A + (size_t)(row0 + (g0 >> 2)) * K + (g0 & 3) * 8;
    const __hip_bfloat16* Ap1 = A + (size_t)(row0 + (g1 >> 2)) * K + (g1 & 3) * 8;
    const __hip_bfloat16* Bp0 = BT + (size_t)(col0 + (g0 >> 2)) * K + (g0 & 3) * 8;
    const __hip_bfloat16* Bp1 = BT + (size_t)(col0 + (g1 >> 2)) * K + (g1 & 3) * 8;
    const int sA0 = (g0 >> 2) * 40 + (g0 & 3) * 8;
    const int sA1 = (g1 >> 2) * 40 + (g1 & 3) * 8;

    f32x4 acc[4][4];
#pragma unroll
    for (int i = 0; i < 4; i++)
#pragma unroll
        for (int j = 0; j < 4; j++) acc[i][j] = (f32x4){0.f, 0.f, 0.f, 0.f};

    const int fr = lane & 15;
    const int fq = (lane >> 4) * 8;

    for (int k0 = 0; k0 < K; k0 += 32) {
        uint4 a0 = *(const uint4*)Ap0;
        uint4 a1 = *(const uint4*)Ap1;
        uint4 b0 = *(const uint4*)Bp0;
        uint4 b1 = *(const uint4*)Bp1;
        Ap0 += 32; Ap1 += 32; Bp0 += 32; Bp1 += 32;
        __syncthreads();
        *(uint4*)&As[sA0] = a0;
        *(uint4*)&As[sA1] = a1;
        *(uint4*)&Bs[sA0] = b0;
        *(uint4*)&Bs[sA1] = b1;
        __syncthreads();

        bf16x8 af[4], bfr[4];
#pragma unroll
        for (int i = 0; i < 4; i++)
            af[i] = *(const bf16x8*)&As[(wm + i * 16 + fr) * 40 + fq];
#pragma unroll
        for (int j = 0; j < 4; j++)
            bfr[j] = *(const bf16x8*)&Bs[(wn + j * 16 + fr) * 40 + fq];
#pragma unroll
        for (int i = 0; i < 4; i++)
#pragma unroll
            for (int j = 0; j < 4; j++)
                acc[i][j] = __builtin_amdgcn_mfma_f32_16x16x32_bf16(af[i], bfr[j], acc[i][j], 0, 0, 0);
    }

    // epilogue: C/D layout col=lane&15, row=(lane>>4)*4+reg
    const int cr = (lane >> 4) * 4;
    const int cc = lane & 15;
#pragma unroll
    for (int i = 0; i < 4; i++)
#pragma unroll
        for (int j = 0; j < 4; j++) {
            size_t base = (size_t)(row0 + wm + i * 16 + cr) * N + (col0 + wn + j * 16 + cc);
#pragma unroll
            for (int p = 0; p < 4; p++) {
                if (c_bf16)
                    ((__hip_bfloat16*)C)[base + (size_t)p * N] = __float2bfloat16(acc[i][j][p]);
                else
                    ((float*)C)[base + (size_t)p * N] = acc[i][j][p];
            }
        }
}

// ---------------------------------------------------------------------------
// Causal depthwise conv (K=4) + SiLU + optional l2norm(+scale). bf16 in/out.
// grid: Bb*Ls*NH, 128 threads.
// ---------------------------------------------------------------------------
__global__ void conv_silu_norm(const __hip_bfloat16* __restrict__ pre, const float* __restrict__ w,
                               __hip_bfloat16* __restrict__ out, int NH, int do_norm, float scale)
{
    __shared__ float red[2];
    const int idx = blockIdx.x;
    const int head = idx % NH;
    const int l = (idx / NH) % Ls;
    const int b = idx / (NH * Ls);
    const int C = NH * Dh;
    const int c = head * Dh + threadIdx.x;
    const __hip_bfloat16* base = pre + ((size_t)b * Ls + l) * C + c;
    const float4 wv = *(const float4*)(w + (size_t)c * 4);

    float v0 = (l >= 3) ? __bfloat162float(base[-3 * C]) : 0.f;
    float v1 = (l >= 2) ? __bfloat162float(base[-2 * C]) : 0.f;
    float v2 = (l >= 1) ? __bfloat162float(base[-1 * C]) : 0.f;
    float v3 = __bfloat162float(base[0]);
    float y = v0 * wv.x + v1 * wv.y + v2 * wv.z + v3 * wv.w;
    y = y / (1.f + expf(-y));   // SiLU

    if (do_norm) {
        float ss = y * y;
#pragma unroll
        for (int off = 32; off > 0; off >>= 1) ss += __shfl_xor(ss, off);
        if ((threadIdx.x & 63) == 0) red[threadIdx.x >> 6] = ss;
        __syncthreads();
        float tot = red[0] + red[1];
        y = y * rsqrtf(tot + 1e-6f) * scale;
    }
    out[((size_t)b * Ls + l) * C + c] = __float2bfloat16(y);
}

// ---------------------------------------------------------------------------
// beta = sigmoid(x@Wb), g = -exp(A_log)*softplus(x@Wgk+dt_bias). fp32 x.
// ---------------------------------------------------------------------------
__global__ void proj_small(const float* __restrict__ x, const float* __restrict__ Wb,
                           const float* __restrict__ Wgk, const float* __restrict__ A_log,
                           const float* __restrict__ dt_bias,
                           float* __restrict__ beta, float* __restrict__ g)
{
    const int row = blockIdx.x;
    const float* xr = x + (size_t)row * DHc;
    float accb[16], accg[16];
#pragma unroll
    for (int i = 0; i < 16; i++) { accb[i] = 0.f; accg[i] = 0.f; }

    for (int t = threadIdx.x; t < DHc; t += 64) {
        float xv = xr[t];
        const float* wb = Wb + (size_t)t * 16;
        const float* wg = Wgk + (size_t)t * 16;
#pragma unroll
        for (int hh = 0; hh < 16; hh++) {
            accb[hh] += xv * wb[hh];
            accg[hh] += xv * wg[hh];
        }
    }
#pragma unroll
    for (int hh = 0; hh < 16; hh++) {
        float vb = accb[hh], vg = accg[hh];
#pragma unroll
        for (int off = 32; off > 0; off >>= 1) {
            vb += __shfl_xor(vb, off);
            vg += __shfl_xor(vg, off);
        }
        if (threadIdx.x == 0) {
            beta[(size_t)row * 16 + hh] = 1.f / (1.f + expf(-vb));
            float z = vg + dt_bias[hh];
            float sp = (z > 20.f) ? z : log1pf(expf(z));
            g[(size_t)row * 16 + hh] = -expf(A_log[hh]) * sp;
        }
    }
}

// ---------------------------------------------------------------------------
// Gated delta-rule recurrence, 2-wave k-split.
// grid = B*H*2 blocks x 128 threads. Block (b,h,half): 64 v-columns.
// Wave w owns state rows [w*64, w*64+64); thread (w,l) holds S[rows][col] for
// col = half*64+l in 64 VGPRs. k kept in registers after pass1.
// ---------------------------------------------------------------------------
__launch_bounds__(128)
__global__ void gdn_recurrence(const __hip_bfloat16* __restrict__ qc, const __hip_bfloat16* __restrict__ kc,
                               const __hip_bfloat16* __restrict__ vc, const float* __restrict__ beta,
                               const float* __restrict__ g, __hip_bfloat16* __restrict__ o)
{
    const int tid = threadIdx.x;
    const int w = tid >> 6, l = tid & 63;
    const int blk = blockIdx.x;
    const int half = blk & 1;
    const int h = (blk >> 1) & 15;
    const int b = blk >> 5;
    const int hk = h >> 2;
    const int col = half * 64 + l;

    __shared__ float sk[128], sq[128], pp[128], po[128];

    float s[64];
#pragma unroll
    for (int i = 0; i < 64; i++) s[i] = 0.f;

    const __hip_bfloat16* krow = kc + ((size_t)b * Ls * HKc + hk) * Dh + tid;
    const __hip_bfloat16* qrow = qc + ((size_t)b * Ls * Hc + h) * Dh + tid;
    const __hip_bfloat16* vrow = vc + ((size_t)b * Ls * HKc + hk) * Dh + col;
    const float* grow = g + (size_t)b * Ls * Hc + h;
    const float* brow = beta + (size_t)b * Ls * Hc + h;
    __hip_bfloat16* orow = o + ((size_t)b * Ls * Hc + h) * Dh + col;

    float pk = __bfloat162float(*krow);
    float pq = __bfloat162float(*qrow);
    float pv = __bfloat162float(*vrow);
    float pg = *grow, pb = *brow;

    for (int t = 0; t < Ls; ++t) {
        sk[tid] = pk;
        sq[tid] = pq;
        const float vt = pv, gt = pg, bt = pb;
        __syncthreads();                       // A: sk/sq visible
        if (t + 1 < Ls) {                      // prefetch next step
            krow += HKc * Dh; qrow += Hc * Dh; vrow += HKc * Dh; grow += Hc; brow += Hc;
            pk = __bfloat162float(*krow);
            pq = __bfloat162float(*qrow);
            pv = __bfloat162float(*vrow);
            pg = *grow; pb = *brow;
        }
        const float eg = expf(gt);

        // pass 1: partial k . S over my 64 rows; keep k in registers
        const float4* sk4 = (const float4*)sk + w * 16;
        float kk[64];
        float a0 = 0.f, a1 = 0.f, a2 = 0.f, a3 = 0.f;
#pragma unroll
        for (int i = 0; i < 16; i++) {
            float4 kv = sk4[i];
            kk[4 * i] = kv.x; kk[4 * i + 1] = kv.y; kk[4 * i + 2] = kv.z; kk[4 * i + 3] = kv.w;
            a0 = fmaf(kv.x, s[4 * i], a0);
            a1 = fmaf(kv.y, s[4 * i + 1], a1);
            a2 = fmaf(kv.z, s[4 * i + 2], a2);
            a3 = fmaf(kv.w, s[4 * i + 3], a3);
        }
        pp[tid] = (a0 + a1) + (a2 + a3);
        __syncthreads();                       // B: partials visible
        const float acck = pp[l] + pp[64 + l];
        const float bv = bt * (vt - eg * acck);

        // pass 2: state update + partial o = q . S_new
        const float4* sq4 = (const float4*)sq + w * 16;
        float o0 = 0.f, o1 = 0.f, o2 = 0.f, o3 = 0.f;
#pragma unroll
        for (int i = 0; i < 16; i++) {
            float4 qv = sq4[i];
            float n0 = fmaf(eg, s[4 * i],     kk[4 * i] * bv);     s[4 * i]     = n0; o0 = fmaf(qv.x, n0, o0);
            float n1 = fmaf(eg, s[4 * i + 1], kk[4 * i + 1] * bv); s[4 * i + 1] = n1; o1 = fmaf(qv.y, n1, o1);
            float n2 = fmaf(eg, s[4 * i + 2], kk[4 * i + 2] * bv); s[4 * i + 2] = n2; o2 = fmaf(qv.z, n2, o2);
            float n3 = fmaf(eg, s[4 * i + 3], kk[4 * i + 3] * bv); s[4 * i + 3] = n3; o3 = fmaf(qv.w, n3, o3);
        }
        po[tid] = (o0 + o1) + (o2 + o3);
        __syncthreads();                       // C: partials visible
        if (w == 0) {
            float ov = po[l] + po[64 + l];
            *orow = __float2bfloat16(ov);
            orow += Hc * Dh;
        }
    }
}

// ---------------------------------------------------------------------------
// FusedRMSNormGated, in place on bf16 o; gate bf16.
// ---------------------------------------------------------------------------
__global__ void gated_rmsnorm(__hip_bfloat16* __restrict__ o, const __hip_bfloat16* __restrict__ gate,
                              const float* __restrict__ w)
{
    const size_t row = blockIdx.x;
    __hip_bfloat16* op = o + row * Dh;
    const __hip_bfloat16* gp = gate + row * Dh;
    const int t = threadIdx.x;
    float o0 = __bfloat162float(op[t]), o1 = __bfloat162float(op[t + 64]);
    float ss = o0 * o0 + o1 * o1;
#pragma unroll
    for (int off = 32; off > 0; off >>= 1) ss += __shfl_xor(ss, off);
    float r = rsqrtf(ss * (1.f / 128.f) + 1e-5f);
    float g0 = __bfloat162float(gp[t]), g1 = __bfloat162float(gp[t + 64]);
    op[t]      = __float2bfloat16(o0 * r * w[t]      * (g0 / (1.f + expf(-g0))));
    op[t + 64] = __float2bfloat16(o1 * r * w[t + 64] * (g1 / (1.f + expf(-g1))));
}

// ---------------------------------------------------------------------------
extern "C" void kernel_launch(void* const* d_in, const int* in_sizes, int n_in,
                              void* d_out, int out_size, void* d_ws, size_t ws_size,
                              hipStream_t stream)
{
    const float* x     = (const float*)d_in[0];
    const float* Wq    = (const float*)d_in[1];
    const float* Wk    = (const float*)d_in[2];
    const float* Wv    = (const float*)d_in[3];
    const float* Wb    = (const float*)d_in[4];
    const float* Wgk   = (const float*)d_in[5];
    const float* A_log = (const float*)d_in[6];
    const float* dtb   = (const float*)d_in[7];
    const float* cq    = (const float*)d_in[8];
    const float* ck    = (const float*)d_in[9];
    const float* cv    = (const float*)d_in[10];
    const float* Wg    = (const float*)d_in[11];
    const float* onw   = (const float*)d_in[12];
    const float* Wo    = (const float*)d_in[13];
    float* out = (float*)d_out;

    // workspace layout (float units); total 19.0M floats = 76.0 MB
    float* ws = (float*)d_ws;
    const size_t F_PRE = (size_t)Mrows * DHc / 2;   // 4,194,304
    const size_t F_KV  = (size_t)Mrows * 512 / 2;   // 1,048,576
    const size_t F_BG  = (size_t)Mrows * Hc;        // 65,536
    __hip_bfloat16* pre = (__hip_bfloat16*)ws;                              // [4096,2048] bf16 (pre-act, later gate)
    __hip_bfloat16* qcb = (__hip_bfloat16*)(ws + F_PRE);                    // [4096,16,128] bf16; later BT2
    __hip_bfloat16* kcb = (__hip_bfloat16*)(ws + 2 * F_PRE);                // [4096,4,128] bf16
    __hip_bfloat16* vcb = (__hip_bfloat16*)(ws + 2 * F_PRE + F_KV);         // [4096,4,128] bf16
    float* bb = ws + 2 * F_PRE + 2 * F_KV;                                  // [4096,16] f32
    float* gb = bb + F_BG;                                                  // [4096,16] f32
    __hip_bfloat16* ob  = (__hip_bfloat16*)(gb + F_BG);                     // [4096,2048] bf16 (o; early: BT)
    __hip_bfloat16* xbf = (__hip_bfloat16*)(gb + F_BG + F_PRE);             // [4096,2048] bf16
    __hip_bfloat16* BT  = ob;   // weight transpose buffer (dead region pre-recurrence)
    __hip_bfloat16* BT2 = qcb;  // Wo transpose (qc dead post-recurrence)

    const float qscale = 0.08838834764831845f; // D^-0.5
    const int nx = Mrows * DHc;

    f32_to_bf16<<<nx / 4 / 256, 256, 0, stream>>>(x, xbf, nx);

    // q: Wq^T, gemm, conv+silu+l2norm*scale
    transpose_to_bf16<<<dim3(32, 32), 256, 0, stream>>>(Wq, BT, 2048, 2048);
    gemm_bt_bf16<<<dim3(16, 32), 256, 0, stream>>>(xbf, BT, pre, 2048, 2048, 1);
    conv_silu_norm<<<Mrows * HQc, 128, 0, stream>>>(pre, cq, qcb, HQc, 1, qscale);
    // k
    transpose_to_bf16<<<dim3(8, 32), 256, 0, stream>>>(Wk, BT, 2048, 512);
    gemm_bt_bf16<<<dim3(4, 32), 256, 0, stream>>>(xbf, BT, pre, 512, 2048, 1);
    conv_silu_norm<<<Mrows * HKc, 128, 0, stream>>>(pre, ck, kcb, HKc, 1, 1.0f);
    // v
    transpose_to_bf16<<<dim3(8, 32), 256, 0, stream>>>(Wv, BT, 2048, 512);
    gemm_bt_bf16<<<dim3(4, 32), 256, 0, stream>>>(xbf, BT, pre, 512, 2048, 1);
    conv_silu_norm<<<Mrows * HKc, 128, 0, stream>>>(pre, cv, vcb, HKc, 0, 1.0f);
    // beta / g
    proj_small<<<Mrows, 64, 0, stream>>>(x, Wb, Wgk, A_log, dtb, bb, gb);
    // gate -> pre (bf16)
    transpose_to_bf16<<<dim3(32, 32), 256, 0, stream>>>(Wg, BT, 2048, 2048);
    gemm_bt_bf16<<<dim3(16, 32), 256, 0, stream>>>(xbf, BT, pre, 2048, 2048, 1);
    // recurrence -> ob (bf16)
    gdn_recurrence<<<Bb * Hc * 2, 128, 0, stream>>>(qcb, kcb, vcb, bb, gb, ob);
    // gated rmsnorm in place, then output projection
    gated_rmsnorm<<<Mrows * Hc, 64, 0, stream>>>(ob, pre, onw);
    transpose_to_bf16<<<dim3(32, 32), 256, 0, stream>>>(Wo, BT2, 2048, 2048);
    gemm_bt_bf16<<<dim3(16, 32), 256, 0, stream>>>(ob, BT2, out, 2048, 2048, 0);
}

// Round 4
// 807.506 us; speedup vs baseline: 6.3526x; 2.1490x over previous
//
#include <hip/hip_runtime.h>
#include <hip/hip_bf16.h>
#include <math.h>

#define Bb 4
#define Ls 1024
#define DHc 2048
#define Dh 128
#define HQc 16
#define HKc 4
#define Hc 16
#define Mrows 4096   // Bb*Ls
#define CC 64        // chunk length
#define NCH 16       // chunks per sequence

typedef __attribute__((ext_vector_type(8))) short bf16x8;
typedef __attribute__((ext_vector_type(4))) float f32x4;

__device__ inline unsigned short f2b(float f) {
    __hip_bfloat16 h = __float2bfloat16(f);
    return *(unsigned short*)&h;
}
__device__ inline float b2f(unsigned short u) {
    __hip_bfloat16 h = *(__hip_bfloat16*)&u;
    return __bfloat162float(h);
}
__device__ inline bf16x8 scale_frag(bf16x8 a, float s) {
    union { bf16x8 v; unsigned short u[8]; } x;
    x.v = a;
#pragma unroll
    for (int i = 0; i < 8; i++) x.u[i] = f2b(b2f(x.u[i]) * s);
    return x.v;
}

// ---------------------------------------------------------------------------
// fp32 -> bf16 elementwise convert (n % 4 == 0)
// ---------------------------------------------------------------------------
__global__ void f32_to_bf16(const float* __restrict__ in, __hip_bfloat16* __restrict__ out, int n)
{
    int i = (blockIdx.x * 256 + threadIdx.x) * 4;
    if (i >= n) return;
    float4 v = *(const float4*)(in + i);
    __hip_bfloat16 h[4];
    h[0] = __float2bfloat16(v.x); h[1] = __float2bfloat16(v.y);
    h[2] = __float2bfloat16(v.z); h[3] = __float2bfloat16(v.w);
    *(uint2*)(out + i) = *(uint2*)h;
}

// ---------------------------------------------------------------------------
// Transpose + convert: W fp32 [Krows, Ncols] -> BT bf16 [Ncols, Krows].
// ---------------------------------------------------------------------------
__launch_bounds__(256)
__global__ void transpose_to_bf16(const float* __restrict__ W, __hip_bfloat16* __restrict__ BT,
                                  int Krows, int Ncols)
{
    __shared__ float tile[64][65];
    const int n0 = blockIdx.x * 64, k0 = blockIdx.y * 64;
    const int tx = threadIdx.x & 63, ty = threadIdx.x >> 6;
#pragma unroll
    for (int r = ty; r < 64; r += 4)
        tile[r][tx] = W[(size_t)(k0 + r) * Ncols + n0 + tx];
    __syncthreads();
#pragma unroll
    for (int r = ty; r < 64; r += 4)
        BT[(size_t)(n0 + r) * Krows + k0 + tx] = __float2bfloat16(tile[tx][r]);
}

// ---------------------------------------------------------------------------
// bf16 MFMA GEMM: C[M,N] = A[M,K] @ BT[N,K]^T. 128x128 tile, BK=32.
// ---------------------------------------------------------------------------
__launch_bounds__(256)
__global__ void gemm_bt_bf16(const __hip_bfloat16* __restrict__ A, const __hip_bfloat16* __restrict__ BT,
                             void* __restrict__ C, int N, int K, int c_bf16)
{
    __shared__ __align__(16) unsigned short As[128 * 40];
    __shared__ __align__(16) unsigned short Bs[128 * 40];
    const int tid = threadIdx.x;
    const int lane = tid & 63;
    const int wave = tid >> 6;
    const int wm = (wave >> 1) * 64, wn = (wave & 1) * 64;
    const int row0 = blockIdx.y * 128, col0 = blockIdx.x * 128;

    const int g0 = tid, g1 = tid + 256;
    const __hip_bfloat16* Ap0 = A + (size_t)(row0 + (g0 >> 2)) * K + (g0 & 3) * 8;
    const __hip_bfloat16* Ap1 = A + (size_t)(row0 + (g1 >> 2)) * K + (g1 & 3) * 8;
    const __hip_bfloat16* Bp0 = BT + (size_t)(col0 + (g0 >> 2)) * K + (g0 & 3) * 8;
    const __hip_bfloat16* Bp1 = BT + (size_t)(col0 + (g1 >> 2)) * K + (g1 & 3) * 8;
    const int sA0 = (g0 >> 2) * 40 + (g0 & 3) * 8;
    const int sA1 = (g1 >> 2) * 40 + (g1 & 3) * 8;

    f32x4 acc[4][4];
#pragma unroll
    for (int i = 0; i < 4; i++)
#pragma unroll
        for (int j = 0; j < 4; j++) acc[i][j] = (f32x4){0.f, 0.f, 0.f, 0.f};

    const int fr = lane & 15;
    const int fq = (lane >> 4) * 8;

    for (int k0 = 0; k0 < K; k0 += 32) {
        uint4 a0 = *(const uint4*)Ap0;
        uint4 a1 = *(const uint4*)Ap1;
        uint4 b0 = *(const uint4*)Bp0;
        uint4 b1 = *(const uint4*)Bp1;
        Ap0 += 32; Ap1 += 32; Bp0 += 32; Bp1 += 32;
        __syncthreads();
        *(uint4*)&As[sA0] = a0;
        *(uint4*)&As[sA1] = a1;
        *(uint4*)&Bs[sA0] = b0;
        *(uint4*)&Bs[sA1] = b1;
        __syncthreads();

        bf16x8 af[4], bfr[4];
#pragma unroll
        for (int i = 0; i < 4; i++)
            af[i] = *(const bf16x8*)&As[(wm + i * 16 + fr) * 40 + fq];
#pragma unroll
        for (int j = 0; j < 4; j++)
            bfr[j] = *(const bf16x8*)&Bs[(wn + j * 16 + fr) * 40 + fq];
#pragma unroll
        for (int i = 0; i < 4; i++)
#pragma unroll
            for (int j = 0; j < 4; j++)
                acc[i][j] = __builtin_amdgcn_mfma_f32_16x16x32_bf16(af[i], bfr[j], acc[i][j], 0, 0, 0);
    }

    const int cr = (lane >> 4) * 4;
    const int cc = lane & 15;
#pragma unroll
    for (int i = 0; i < 4; i++)
#pragma unroll
        for (int j = 0; j < 4; j++) {
            size_t base = (size_t)(row0 + wm + i * 16 + cr) * N + (col0 + wn + j * 16 + cc);
#pragma unroll
            for (int p = 0; p < 4; p++) {
                if (c_bf16)
                    ((__hip_bfloat16*)C)[base + (size_t)p * N] = __float2bfloat16(acc[i][j][p]);
                else
                    ((float*)C)[base + (size_t)p * N] = acc[i][j][p];
            }
        }
}

// ---------------------------------------------------------------------------
// Causal depthwise conv (K=4) + SiLU + optional l2norm(+scale). bf16 in/out.
// ---------------------------------------------------------------------------
__global__ void conv_silu_norm(const __hip_bfloat16* __restrict__ pre, const float* __restrict__ w,
                               __hip_bfloat16* __restrict__ out, int NH, int do_norm, float scale)
{
    __shared__ float red[2];
    const int idx = blockIdx.x;
    const int head = idx % NH;
    const int l = (idx / NH) % Ls;
    const int b = idx / (NH * Ls);
    const int C = NH * Dh;
    const int c = head * Dh + threadIdx.x;
    const __hip_bfloat16* base = pre + ((size_t)b * Ls + l) * C + c;
    const float4 wv = *(const float4*)(w + (size_t)c * 4);

    float v0 = (l >= 3) ? __bfloat162float(base[-3 * C]) : 0.f;
    float v1 = (l >= 2) ? __bfloat162float(base[-2 * C]) : 0.f;
    float v2 = (l >= 1) ? __bfloat162float(base[-1 * C]) : 0.f;
    float v3 = __bfloat162float(base[0]);
    float y = v0 * wv.x + v1 * wv.y + v2 * wv.z + v3 * wv.w;
    y = y / (1.f + expf(-y));   // SiLU

    if (do_norm) {
        float ss = y * y;
#pragma unroll
        for (int off = 32; off > 0; off >>= 1) ss += __shfl_xor(ss, off);
        if ((threadIdx.x & 63) == 0) red[threadIdx.x >> 6] = ss;
        __syncthreads();
        float tot = red[0] + red[1];
        y = y * rsqrtf(tot + 1e-6f) * scale;
    }
    out[((size_t)b * Ls + l) * C + c] = __float2bfloat16(y);
}

// ---------------------------------------------------------------------------
// beta = sigmoid(x@Wb), g = -exp(A_log)*softplus(x@Wgk+dt_bias).
// ---------------------------------------------------------------------------
__global__ void proj_small(const float* __restrict__ x, const float* __restrict__ Wb,
                           const float* __restrict__ Wgk, const float* __restrict__ A_log,
                           const float* __restrict__ dt_bias,
                           float* __restrict__ beta, float* __restrict__ g)
{
    const int row = blockIdx.x;
    const float* xr = x + (size_t)row * DHc;
    float accb[16], accg[16];
#pragma unroll
    for (int i = 0; i < 16; i++) { accb[i] = 0.f; accg[i] = 0.f; }

    for (int t = threadIdx.x; t < DHc; t += 64) {
        float xv = xr[t];
        const float* wb = Wb + (size_t)t * 16;
        const float* wg = Wgk + (size_t)t * 16;
#pragma unroll
        for (int hh = 0; hh < 16; hh++) {
            accb[hh] += xv * wb[hh];
            accg[hh] += xv * wg[hh];
        }
    }
#pragma unroll
    for (int hh = 0; hh < 16; hh++) {
        float vb = accb[hh], vg = accg[hh];
#pragma unroll
        for (int off = 32; off > 0; off >>= 1) {
            vb += __shfl_xor(vb, off);
            vg += __shfl_xor(vg, off);
        }
        if (threadIdx.x == 0) {
            beta[(size_t)row * 16 + hh] = 1.f / (1.f + expf(-vb));
            float z = vg + dt_bias[hh];
            float sp = (z > 20.f) ? z : log1pf(expf(z));
            g[(size_t)row * 16 + hh] = -expf(A_log[hh]) * sp;
        }
    }
}

// ---------------------------------------------------------------------------
// Per-chunk inclusive prefix sum of log-decay g. grid = BH*NCH blocks, 64 thr.
// ---------------------------------------------------------------------------
__global__ void bcum_kernel(const float* __restrict__ g, float* __restrict__ bcum)
{
    const int c = blockIdx.x & 15;
    const int bh = blockIdx.x >> 4;
    const int b = bh >> 4;
    const int h = bh & 15;
    const int t = threadIdx.x;
    float v = g[((size_t)(b * Ls + c * CC + t)) * 16 + h];
#pragma unroll
    for (int d = 1; d < 64; d <<= 1) {
        float n = __shfl_up(v, d, 64);
        if (t >= d) v += n;
    }
    bcum[(size_t)blockIdx.x * 64 + t] = v;
}

// ---------------------------------------------------------------------------
// Phase 1 (parallel over 1024 (b,h,chunk) tasks):
//   P = K K^T (MFMA); A[t][s] = beta_t exp(bc_t-bc_s) P (s<t);
//   forward-substitute (I+A)[U|Z] = [diag(beta)V | diag(beta)diag(exp(bc))K]
// ---------------------------------------------------------------------------
__launch_bounds__(256)
__global__ void gdn_phase1(const __hip_bfloat16* __restrict__ kc, const __hip_bfloat16* __restrict__ vc,
                           const float* __restrict__ bb, const float* __restrict__ bcum,
                           __hip_bfloat16* __restrict__ U, __hip_bfloat16* __restrict__ Z)
{
    const int task = blockIdx.x;
    const int c = task & 15;
    const int bh = task >> 4;
    const int b = bh >> 4;
    const int h = bh & 15;
    const int hk = h >> 2;
    const int tid = threadIdx.x;
    const int lane = tid & 63;
    const int wave = tid >> 6;
    const int q = lane >> 4;
    const int cL = lane & 15;

    __shared__ float Ab[64][68];
    __shared__ float sbeta[64], sbc[64];

    if (tid < 64) {
        sbeta[tid] = bb[((size_t)(b * Ls + c * CC + tid)) * 16 + h];
        sbc[tid] = bcum[((size_t)bh * 16 + c) * 64 + tid];
    }
    __syncthreads();

    const unsigned short* ku = (const unsigned short*)kc;
    const unsigned short* vu = (const unsigned short*)vc;

    // P = K K^T : wave w owns rows t in [16w,16w+16)
    f32x4 pacc[4];
#pragma unroll
    for (int j = 0; j < 4; j++) pacc[j] = (f32x4){0.f, 0.f, 0.f, 0.f};
    {
        const int t = 16 * wave + cL;
        const size_t krow = (((size_t)(b * Ls + c * CC + t)) * 4 + hk) * 128;
#pragma unroll
        for (int ks = 0; ks < 4; ks++) {
            bf16x8 af = *(const bf16x8*)&ku[krow + ks * 32 + q * 8];
#pragma unroll
            for (int j = 0; j < 4; j++) {
                const int s = 16 * j + cL;
                bf16x8 bf = *(const bf16x8*)&ku[(((size_t)(b * Ls + c * CC + s)) * 4 + hk) * 128 + ks * 32 + q * 8];
                pacc[j] = __builtin_amdgcn_mfma_f32_16x16x32_bf16(af, bf, pacc[j], 0, 0, 0);
            }
        }
    }
    // dump A (fp32, zero on/above diagonal)
#pragma unroll
    for (int j = 0; j < 4; j++)
#pragma unroll
        for (int p = 0; p < 4; p++) {
            const int t = 16 * wave + 4 * q + p;
            const int s = 16 * j + cL;
            float val = 0.f;
            if (s < t) val = sbeta[t] * __expf(sbc[t] - sbc[s]) * pacc[j][p];
            Ab[t][s] = val;
        }
    __syncthreads();

    // forward substitution, thread = one column of [U | Z]
    float u[64];
    const int j = tid;
    if (j < 128) {
#pragma unroll
        for (int t = 0; t < 64; t++)
            u[t] = sbeta[t] * b2f(vu[(((size_t)(b * Ls + c * CC + t)) * 4 + hk) * 128 + j]);
    } else {
        const int k = j - 128;
#pragma unroll
        for (int t = 0; t < 64; t++)
            u[t] = sbeta[t] * __expf(sbc[t]) * b2f(ku[(((size_t)(b * Ls + c * CC + t)) * 4 + hk) * 128 + k]);
    }
#pragma unroll
    for (int t = 1; t < 64; t++) {
        const float4* ar = (const float4*)Ab[t];
        const int nf = (t + 3) >> 2;
        float a0 = 0.f, a1 = 0.f, a2 = 0.f, a3 = 0.f;
#pragma unroll
        for (int i = 0; i < nf; i++) {
            float4 av = ar[i];
            a0 = fmaf(av.x, u[4 * i + 0], a0);
            a1 = fmaf(av.y, u[4 * i + 1], a1);
            a2 = fmaf(av.z, u[4 * i + 2], a2);
            a3 = fmaf(av.w, u[4 * i + 3], a3);
        }
        u[t] -= (a0 + a1) + (a2 + a3);
    }
    const size_t slab = ((size_t)bh * 16 + c) * 8192;
    if (j < 128) {
#pragma unroll
        for (int t = 0; t < 64; t++) U[slab + t * 128 + j] = __float2bfloat16(u[t]);
    } else {
#pragma unroll
        for (int t = 0; t < 64; t++) Z[slab + t * 128 + (j - 128)] = __float2bfloat16(u[t]);
    }
}

// ---------------------------------------------------------------------------
// Phase 2 (sequential over 16 chunks; 64 parallel (b,h) blocks):
//   W = U - Z T^T ; O1 = (diag(E)Q) T^T ; T = e_C T + W^T K_hat (via MFMA)
// stores W^T (bf16) over the U buffer for phase 3, O1 (fp32) to Obuf.
// ---------------------------------------------------------------------------
__launch_bounds__(256)
__global__ void gdn_phase2(const __hip_bfloat16* __restrict__ qc, const __hip_bfloat16* __restrict__ kc,
                           __hip_bfloat16* Uw /* in: U, out: W^T (aliased) */,
                           const __hip_bfloat16* __restrict__ Zbuf,
                           const float* __restrict__ bcum, float* __restrict__ Obuf)
{
    const int bh = blockIdx.x;
    const int b = bh >> 4;
    const int h = bh & 15;
    const int hk = h >> 2;
    const int tid = threadIdx.x;
    const int lane = tid & 63;
    const int wave = tid >> 6;
    const int q = lane >> 4;
    const int cL = lane & 15;

    __shared__ __align__(16) unsigned short Tb[128 * 72];  // T[v][k-half], split over k
    __shared__ __align__(16) unsigned short Wt[128 * 72];  // W^T[v][t]
    __shared__ __align__(16) unsigned short Kt[128 * 72];  // K_hat^T[k][t]

    const unsigned short* qu = (const unsigned short*)qc;
    const unsigned short* ku = (const unsigned short*)kc;
    unsigned short* Uu = (unsigned short*)Uw;
    const unsigned short* Zu = (const unsigned short*)Zbuf;

    f32x4 Tacc[2][8];
#pragma unroll
    for (int i = 0; i < 2; i++)
#pragma unroll
        for (int j = 0; j < 8; j++) Tacc[i][j] = (f32x4){0.f, 0.f, 0.f, 0.f};

    for (int c = 0; c < NCH; ++c) {
        const float* bc = bcum + ((size_t)bh * 16 + c) * 64;
        const size_t slab = ((size_t)bh * 16 + c) * 8192;
        __syncthreads();  // A: prev chunk's G3 done with Wt/Kt; prev readers done with Tb

        // stage K_hat^T into Kt: row k, contiguous t; scale exp(bc[63]-bc[t])
        {
            const int tloc = tid & 63;
            const int g = tid >> 6;
            const float ek = __expf(bc[63] - bc[tloc]);
            const size_t krow = (((size_t)(b * Ls + c * CC + tloc)) * 4 + hk) * 128 + g * 32;
#pragma unroll
            for (int m = 0; m < 4; m++) {
                union { bf16x8 v; unsigned short us[8]; } kv;
                kv.v = scale_frag(*(const bf16x8*)&ku[krow + m * 8], ek);
#pragma unroll
                for (int e = 0; e < 8; e++) Kt[(g * 32 + m * 8 + e) * 72 + tloc] = kv.us[e];
            }
        }
        // dump T columns k=0..63 (acc tiles j=0..3)
#pragma unroll
        for (int i = 0; i < 2; i++)
#pragma unroll
            for (int jj = 0; jj < 4; jj++)
#pragma unroll
                for (int p = 0; p < 4; p++) {
                    const int v = 32 * wave + 16 * i + 4 * q + p;
                    Tb[v * 72 + 16 * jj + cL] = f2b(Tacc[i][jj][p]);
                }
        __syncthreads();  // B1

        f32x4 Wacc[8], Oacc[8];
#pragma unroll
        for (int j = 0; j < 8; j++) { Wacc[j] = (f32x4){0.f,0.f,0.f,0.f}; Oacc[j] = (f32x4){0.f,0.f,0.f,0.f}; }
        const int trow = 16 * wave + cL;                    // A-frag row (chunk-local t)
        const float Et = __expf(bc[trow]);
        const size_t zrow = slab + (size_t)trow * 128;
        const size_t qrow = (((size_t)(b * Ls + c * CC + trow)) * 16 + h) * 128;

        // G1+G2, k-steps 0..1 (T columns 0..63)
#pragma unroll
        for (int ksl = 0; ksl < 2; ksl++) {
            bf16x8 az = *(const bf16x8*)&Zu[zrow + ksl * 32 + q * 8];
            bf16x8 aq = scale_frag(*(const bf16x8*)&qu[qrow + ksl * 32 + q * 8], Et);
#pragma unroll
            for (int j = 0; j < 8; j++) {
                bf16x8 bt = *(const bf16x8*)&Tb[(16 * j + cL) * 72 + ksl * 32 + q * 8];
                Wacc[j] = __builtin_amdgcn_mfma_f32_16x16x32_bf16(az, bt, Wacc[j], 0, 0, 0);
                Oacc[j] = __builtin_amdgcn_mfma_f32_16x16x32_bf16(aq, bt, Oacc[j], 0, 0, 0);
            }
        }
        __syncthreads();  // B2: everyone done reading Tb half 1
        // dump T columns k=64..127 (acc tiles j=4..7)
#pragma unroll
        for (int i = 0; i < 2; i++)
#pragma unroll
            for (int jj = 0; jj < 4; jj++)
#pragma unroll
                for (int p = 0; p < 4; p++) {
                    const int v = 32 * wave + 16 * i + 4 * q + p;
                    Tb[v * 72 + 16 * jj + cL] = f2b(Tacc[i][4 + jj][p]);
                }
        __syncthreads();  // B3
#pragma unroll
        for (int ksl = 0; ksl < 2; ksl++) {
            bf16x8 az = *(const bf16x8*)&Zu[zrow + 64 + ksl * 32 + q * 8];
            bf16x8 aq = scale_frag(*(const bf16x8*)&qu[qrow + 64 + ksl * 32 + q * 8], Et);
#pragma unroll
            for (int j = 0; j < 8; j++) {
                bf16x8 bt = *(const bf16x8*)&Tb[(16 * j + cL) * 72 + ksl * 32 + q * 8];
                Wacc[j] = __builtin_amdgcn_mfma_f32_16x16x32_bf16(az, bt, Wacc[j], 0, 0, 0);
                Oacc[j] = __builtin_amdgcn_mfma_f32_16x16x32_bf16(aq, bt, Oacc[j], 0, 0, 0);
            }
        }
        // O1 store (fp32) + W = U - Wacc, dump W^T into Wt
#pragma unroll
        for (int j = 0; j < 8; j++)
#pragma unroll
            for (int p = 0; p < 4; p++) {
                const int t = 16 * wave + 4 * q + p;
                const int v = 16 * j + cL;
                Obuf[((size_t)(b * Ls + c * CC + t)) * 2048 + h * 128 + v] = Oacc[j][p];
                const float w = b2f(Uu[slab + t * 128 + v]) - Wacc[j][p];
                Wt[v * 72 + t] = f2b(w);
            }
        __syncthreads();  // C: Wt complete, U reads of this slab done

        // store W^T to global (over U slab), coalesced from LDS.
        // NOTE: uint4 = 8 shorts -> stride 8 (round-3 bug was stride 16, leaving gaps)
        {
            const int v = tid >> 1;
            const int half = tid & 1;
#pragma unroll
            for (int m = 0; m < 4; m++) {
                uint4 val = *(const uint4*)&Wt[v * 72 + half * 32 + m * 8];
                *(uint4*)&Uu[slab + (size_t)v * 64 + half * 32 + m * 8] = val;
            }
        }
        // G3: T = e_C * T + W^T K_hat
        const float eC = __expf(bc[63]);
#pragma unroll
        for (int i = 0; i < 2; i++)
#pragma unroll
            for (int j = 0; j < 8; j++)
#pragma unroll
                for (int p = 0; p < 4; p++) Tacc[i][j][p] *= eC;
#pragma unroll
        for (int ks = 0; ks < 2; ks++) {
            bf16x8 aw[2];
#pragma unroll
            for (int i = 0; i < 2; i++)
                aw[i] = *(const bf16x8*)&Wt[(32 * wave + 16 * i + cL) * 72 + ks * 32 + q * 8];
#pragma unroll
            for (int j = 0; j < 8; j++) {
                bf16x8 bk = *(const bf16x8*)&Kt[(16 * j + cL) * 72 + ks * 32 + q * 8];
                Tacc[0][j] = __builtin_amdgcn_mfma_f32_16x16x32_bf16(aw[0], bk, Tacc[0][j], 0, 0, 0);
                Tacc[1][j] = __builtin_amdgcn_mfma_f32_16x16x32_bf16(aw[1], bk, Tacc[1][j], 0, 0, 0);
            }
        }
    }
}

// ---------------------------------------------------------------------------
// Phase 3 (parallel over 1024 (b,h,chunk) tasks):
//   M[t][s] = exp(bc_t-bc_s) (q_t.k_s), s<=t;  O += M W  (W^T read from Uw)
// ---------------------------------------------------------------------------
__launch_bounds__(256)
__global__ void gdn_phase3(const __hip_bfloat16* __restrict__ qc, const __hip_bfloat16* __restrict__ kc,
                           const __hip_bfloat16* __restrict__ WT, const float* __restrict__ bcum,
                           float* __restrict__ Obuf)
{
    const int task = blockIdx.x;
    const int c = task & 15;
    const int bh = task >> 4;
    const int b = bh >> 4;
    const int h = bh & 15;
    const int hk = h >> 2;
    const int tid = threadIdx.x;
    const int lane = tid & 63;
    const int wave = tid >> 6;
    const int q = lane >> 4;
    const int cL = lane & 15;

    __shared__ __align__(16) unsigned short Mb[64 * 72];
    __shared__ float sbc[64];

    if (tid < 64) sbc[tid] = bcum[((size_t)bh * 16 + c) * 64 + tid];
    __syncthreads();

    const unsigned short* qu = (const unsigned short*)qc;
    const unsigned short* ku = (const unsigned short*)kc;
    const unsigned short* wu = (const unsigned short*)WT;

    // Pq = Q K^T
    f32x4 pacc[4];
#pragma unroll
    for (int j = 0; j < 4; j++) pacc[j] = (f32x4){0.f, 0.f, 0.f, 0.f};
    {
        const int t = 16 * wave + cL;
        const size_t qrow = (((size_t)(b * Ls + c * CC + t)) * 16 + h) * 128;
#pragma unroll
        for (int ks = 0; ks < 4; ks++) {
            bf16x8 aq = *(const bf16x8*)&qu[qrow + ks * 32 + q * 8];
#pragma unroll
            for (int j = 0; j < 4; j++) {
                const int s = 16 * j + cL;
                bf16x8 bk = *(const bf16x8*)&ku[(((size_t)(b * Ls + c * CC + s)) * 4 + hk) * 128 + ks * 32 + q * 8];
                pacc[j] = __builtin_amdgcn_mfma_f32_16x16x32_bf16(aq, bk, pacc[j], 0, 0, 0);
            }
        }
    }
#pragma unroll
    for (int j = 0; j < 4; j++)
#pragma unroll
        for (int p = 0; p < 4; p++) {
            const int t = 16 * wave + 4 * q + p;
            const int s = 16 * j + cL;
            const float val = (s <= t) ? __expf(sbc[t] - sbc[s]) * pacc[j][p] : 0.f;
            Mb[t * 72 + s] = f2b(val);
        }
    __syncthreads();

    // O2 = M W ; B-frags from W^T (global, contiguous)
    f32x4 oacc[8];
#pragma unroll
    for (int j = 0; j < 8; j++) oacc[j] = (f32x4){0.f, 0.f, 0.f, 0.f};
    const size_t slab = ((size_t)bh * 16 + c) * 8192;
#pragma unroll
    for (int ks = 0; ks < 2; ks++) {
        bf16x8 am = *(const bf16x8*)&Mb[(16 * wave + cL) * 72 + ks * 32 + q * 8];
#pragma unroll
        for (int j = 0; j < 8; j++) {
            const int v = 16 * j + cL;
            bf16x8 bw = *(const bf16x8*)&wu[slab + (size_t)v * 64 + ks * 32 + q * 8];
            oacc[j] = __builtin_amdgcn_mfma_f32_16x16x32_bf16(am, bw, oacc[j], 0, 0, 0);
        }
    }
#pragma unroll
    for (int j = 0; j < 8; j++)
#pragma unroll
        for (int p = 0; p < 4; p++) {
            const int t = 16 * wave + 4 * q + p;
            const int v = 16 * j + cL;
            const size_t a = ((size_t)(b * Ls + c * CC + t)) * 2048 + h * 128 + v;
            Obuf[a] += oacc[j][p];
        }
}

// ---------------------------------------------------------------------------
// FusedRMSNormGated: reads fp32 o, bf16 gate; writes bf16 normalized o.
// ---------------------------------------------------------------------------
__global__ void gated_rmsnorm(const float* __restrict__ o, const __hip_bfloat16* __restrict__ gate,
                              const float* __restrict__ w, __hip_bfloat16* __restrict__ out)
{
    const size_t row = blockIdx.x;
    const float* op = o + row * Dh;
    const __hip_bfloat16* gp = gate + row * Dh;
    const int t = threadIdx.x;
    float o0 = op[t], o1 = op[t + 64];
    float ss = o0 * o0 + o1 * o1;
#pragma unroll
    for (int off = 32; off > 0; off >>= 1) ss += __shfl_xor(ss, off);
    float r = rsqrtf(ss * (1.f / 128.f) + 1e-5f);
    float g0 = __bfloat162float(gp[t]), g1 = __bfloat162float(gp[t + 64]);
    out[row * Dh + t]      = __float2bfloat16(o0 * r * w[t]      * (g0 / (1.f + expf(-g0))));
    out[row * Dh + t + 64] = __float2bfloat16(o1 * r * w[t + 64] * (g1 / (1.f + expf(-g1))));
}

// ---------------------------------------------------------------------------
extern "C" void kernel_launch(void* const* d_in, const int* in_sizes, int n_in,
                              void* d_out, int out_size, void* d_ws, size_t ws_size,
                              hipStream_t stream)
{
    const float* x     = (const float*)d_in[0];
    const float* Wq    = (const float*)d_in[1];
    const float* Wk    = (const float*)d_in[2];
    const float* Wv    = (const float*)d_in[3];
    const float* Wb    = (const float*)d_in[4];
    const float* Wgk   = (const float*)d_in[5];
    const float* A_log = (const float*)d_in[6];
    const float* dtb   = (const float*)d_in[7];
    const float* cq    = (const float*)d_in[8];
    const float* ck    = (const float*)d_in[9];
    const float* cv    = (const float*)d_in[10];
    const float* Wg    = (const float*)d_in[11];
    const float* onw   = (const float*)d_in[12];
    const float* Wo    = (const float*)d_in[13];

    // --- workspace layout (bytes), total 75,759,616 B ---
    char* wsb = (char*)d_ws;
    __hip_bfloat16* xbf  = (__hip_bfloat16*)(wsb + 0);          // [4096,2048]   16.78 MB
    __hip_bfloat16* qcb  = (__hip_bfloat16*)(wsb + 16777216);   // [4096,16,128] 16.78 MB
    __hip_bfloat16* kcb  = (__hip_bfloat16*)(wsb + 33554432);   // [4096,4,128]   4.19 MB
    __hip_bfloat16* vcb  = (__hip_bfloat16*)(wsb + 37748736);   // [4096,4,128]   4.19 MB
    __hip_bfloat16* Uw   = (__hip_bfloat16*)(wsb + 41943040);   // U then W^T    16.78 MB
    __hip_bfloat16* Zb   = (__hip_bfloat16*)(wsb + 58720256);   // Z then gate   16.78 MB
    float*          bcum = (float*)(wsb + 75497472);            // [64,16,64]     0.26 MB

    // --- d_out doubles as early scratch (dead before phase 2 writes O) ---
    char* dob = (char*)d_out;
    __hip_bfloat16* pre = (__hip_bfloat16*)dob;                 // conv pre-acts (<=16.78 MB)
    __hip_bfloat16* BT  = (__hip_bfloat16*)(dob + 16777216);    // weight transposes (<=8.39 MB)
    float* bb = (float*)(dob + 25165824);                       // beta [4096,16]
    float* gb = (float*)(dob + 25427968);                       // g    [4096,16]
    float* Obuf = (float*)d_out;                                // fp32 O [4096,2048]

    const float qscale = 0.08838834764831845f; // D^-0.5
    const int nx = Mrows * DHc;

    f32_to_bf16<<<nx / 4 / 256, 256, 0, stream>>>(x, xbf, nx);
    proj_small<<<Mrows, 64, 0, stream>>>(x, Wb, Wgk, A_log, dtb, bb, gb);
    bcum_kernel<<<64 * NCH, 64, 0, stream>>>(gb, bcum);

    // q
    transpose_to_bf16<<<dim3(32, 32), 256, 0, stream>>>(Wq, BT, 2048, 2048);
    gemm_bt_bf16<<<dim3(16, 32), 256, 0, stream>>>(xbf, BT, pre, 2048, 2048, 1);
    conv_silu_norm<<<Mrows * HQc, 128, 0, stream>>>(pre, cq, qcb, HQc, 1, qscale);
    // k
    transpose_to_bf16<<<dim3(8, 32), 256, 0, stream>>>(Wk, BT, 2048, 512);
    gemm_bt_bf16<<<dim3(4, 32), 256, 0, stream>>>(xbf, BT, pre, 512, 2048, 1);
    conv_silu_norm<<<Mrows * HKc, 128, 0, stream>>>(pre, ck, kcb, HKc, 1, 1.0f);
    // v
    transpose_to_bf16<<<dim3(8, 32), 256, 0, stream>>>(Wv, BT, 2048, 512);
    gemm_bt_bf16<<<dim3(4, 32), 256, 0, stream>>>(xbf, BT, pre, 512, 2048, 1);
    conv_silu_norm<<<Mrows * HKc, 128, 0, stream>>>(pre, cv, vcb, HKc, 0, 1.0f);

    // chunked delta-rule
    gdn_phase1<<<64 * NCH, 256, 0, stream>>>(kcb, vcb, bb, bcum, Uw, Zb);
    gdn_phase2<<<64, 256, 0, stream>>>(qcb, kcb, Uw, Zb, bcum, Obuf);
    gdn_phase3<<<64 * NCH, 256, 0, stream>>>(qcb, kcb, Uw, bcum, Obuf);

    // gate projection (into Zb; Z dead after phase 2), rmsnorm, output proj
    transpose_to_bf16<<<dim3(32, 32), 256, 0, stream>>>(Wg, (__hip_bfloat16*)Uw, 2048, 2048); // Uw dead after phase 3
    gemm_bt_bf16<<<dim3(16, 32), 256, 0, stream>>>(xbf, (__hip_bfloat16*)Uw, Zb, 2048, 2048, 1);
    gated_rmsnorm<<<Mrows * Hc, 64, 0, stream>>>(Obuf, Zb, onw, qcb); // qcb dead after phase 3
    transpose_to_bf16<<<dim3(32, 32), 256, 0, stream>>>(Wo, (__hip_bfloat16*)Uw, 2048, 2048);
    gemm_bt_bf16<<<dim3(16, 32), 256, 0, stream>>>(qcb, (__hip_bfloat16*)Uw, d_out, 2048, 2048, 0);
}

// Round 5
// 732.191 us; speedup vs baseline: 7.0060x; 1.1029x over previous
//
#include <hip/hip_runtime.h>
#include <hip/hip_bf16.h>
#include <math.h>

#define Bb 4
#define Ls 1024
#define DHc 2048
#define Dh 128
#define HQc 16
#define HKc 4
#define Hc 16
#define Mrows 4096   // Bb*Ls
#define CC 64        // chunk length
#define NCH 16       // chunks per sequence

typedef __attribute__((ext_vector_type(8))) short bf16x8;
typedef __attribute__((ext_vector_type(4))) float f32x4;

__device__ inline unsigned short f2b(float f) {
    __hip_bfloat16 h = __float2bfloat16(f);
    return *(unsigned short*)&h;
}
__device__ inline float b2f(unsigned short u) {
    __hip_bfloat16 h = *(__hip_bfloat16*)&u;
    return __bfloat162float(h);
}
__device__ inline bf16x8 scale_frag(bf16x8 a, float s) {
    union { bf16x8 v; unsigned short u[8]; } x;
    x.v = a;
#pragma unroll
    for (int i = 0; i < 8; i++) x.u[i] = f2b(b2f(x.u[i]) * s);
    return x.v;
}

// ---------------------------------------------------------------------------
// fp32 -> bf16 elementwise convert (n % 4 == 0)
// ---------------------------------------------------------------------------
__global__ void f32_to_bf16(const float* __restrict__ in, __hip_bfloat16* __restrict__ out, int n)
{
    int i = (blockIdx.x * 256 + threadIdx.x) * 4;
    if (i >= n) return;
    float4 v = *(const float4*)(in + i);
    __hip_bfloat16 h[4];
    h[0] = __float2bfloat16(v.x); h[1] = __float2bfloat16(v.y);
    h[2] = __float2bfloat16(v.z); h[3] = __float2bfloat16(v.w);
    *(uint2*)(out + i) = *(uint2*)h;
}

// ---------------------------------------------------------------------------
// Transpose + convert: W fp32 [Krows, Ncols] -> BT bf16 [Ncols, Krows].
// ---------------------------------------------------------------------------
__launch_bounds__(256)
__global__ void transpose_to_bf16(const float* __restrict__ W, __hip_bfloat16* __restrict__ BT,
                                  int Krows, int Ncols)
{
    __shared__ float tile[64][65];
    const int n0 = blockIdx.x * 64, k0 = blockIdx.y * 64;
    const int tx = threadIdx.x & 63, ty = threadIdx.x >> 6;
#pragma unroll
    for (int r = ty; r < 64; r += 4)
        tile[r][tx] = W[(size_t)(k0 + r) * Ncols + n0 + tx];
    __syncthreads();
#pragma unroll
    for (int r = ty; r < 64; r += 4)
        BT[(size_t)(n0 + r) * Krows + k0 + tx] = __float2bfloat16(tile[tx][r]);
}

// ---------------------------------------------------------------------------
// bf16 MFMA GEMM: C[M,N] = A[M,K] @ BT[N,K]^T. 128x128 tile, BK=32.
// ---------------------------------------------------------------------------
__launch_bounds__(256)
__global__ void gemm_bt_bf16(const __hip_bfloat16* __restrict__ A, const __hip_bfloat16* __restrict__ BT,
                             void* __restrict__ C, int N, int K, int c_bf16)
{
    __shared__ __align__(16) unsigned short As[128 * 40];
    __shared__ __align__(16) unsigned short Bs[128 * 40];
    const int tid = threadIdx.x;
    const int lane = tid & 63;
    const int wave = tid >> 6;
    const int wm = (wave >> 1) * 64, wn = (wave & 1) * 64;
    const int row0 = blockIdx.y * 128, col0 = blockIdx.x * 128;

    const int g0 = tid, g1 = tid + 256;
    const __hip_bfloat16* Ap0 = A + (size_t)(row0 + (g0 >> 2)) * K + (g0 & 3) * 8;
    const __hip_bfloat16* Ap1 = A + (size_t)(row0 + (g1 >> 2)) * K + (g1 & 3) * 8;
    const __hip_bfloat16* Bp0 = BT + (size_t)(col0 + (g0 >> 2)) * K + (g0 & 3) * 8;
    const __hip_bfloat16* Bp1 = BT + (size_t)(col0 + (g1 >> 2)) * K + (g1 & 3) * 8;
    const int sA0 = (g0 >> 2) * 40 + (g0 & 3) * 8;
    const int sA1 = (g1 >> 2) * 40 + (g1 & 3) * 8;

    f32x4 acc[4][4];
#pragma unroll
    for (int i = 0; i < 4; i++)
#pragma unroll
        for (int j = 0; j < 4; j++) acc[i][j] = (f32x4){0.f, 0.f, 0.f, 0.f};

    const int fr = lane & 15;
    const int fq = (lane >> 4) * 8;

    for (int k0 = 0; k0 < K; k0 += 32) {
        uint4 a0 = *(const uint4*)Ap0;
        uint4 a1 = *(const uint4*)Ap1;
        uint4 b0 = *(const uint4*)Bp0;
        uint4 b1 = *(const uint4*)Bp1;
        Ap0 += 32; Ap1 += 32; Bp0 += 32; Bp1 += 32;
        __syncthreads();
        *(uint4*)&As[sA0] = a0;
        *(uint4*)&As[sA1] = a1;
        *(uint4*)&Bs[sA0] = b0;
        *(uint4*)&Bs[sA1] = b1;
        __syncthreads();

        bf16x8 af[4], bfr[4];
#pragma unroll
        for (int i = 0; i < 4; i++)
            af[i] = *(const bf16x8*)&As[(wm + i * 16 + fr) * 40 + fq];
#pragma unroll
        for (int j = 0; j < 4; j++)
            bfr[j] = *(const bf16x8*)&Bs[(wn + j * 16 + fr) * 40 + fq];
#pragma unroll
        for (int i = 0; i < 4; i++)
#pragma unroll
            for (int j = 0; j < 4; j++)
                acc[i][j] = __builtin_amdgcn_mfma_f32_16x16x32_bf16(af[i], bfr[j], acc[i][j], 0, 0, 0);
    }

    const int cr = (lane >> 4) * 4;
    const int cc = lane & 15;
#pragma unroll
    for (int i = 0; i < 4; i++)
#pragma unroll
        for (int j = 0; j < 4; j++) {
            size_t base = (size_t)(row0 + wm + i * 16 + cr) * N + (col0 + wn + j * 16 + cc);
#pragma unroll
            for (int p = 0; p < 4; p++) {
                if (c_bf16)
                    ((__hip_bfloat16*)C)[base + (size_t)p * N] = __float2bfloat16(acc[i][j][p]);
                else
                    ((float*)C)[base + (size_t)p * N] = acc[i][j][p];
            }
        }
}

// ---------------------------------------------------------------------------
// Causal depthwise conv (K=4) + SiLU + optional l2norm(+scale). bf16 in/out.
// ---------------------------------------------------------------------------
__global__ void conv_silu_norm(const __hip_bfloat16* __restrict__ pre, const float* __restrict__ w,
                               __hip_bfloat16* __restrict__ out, int NH, int do_norm, float scale)
{
    __shared__ float red[2];
    const int idx = blockIdx.x;
    const int head = idx % NH;
    const int l = (idx / NH) % Ls;
    const int b = idx / (NH * Ls);
    const int C = NH * Dh;
    const int c = head * Dh + threadIdx.x;
    const __hip_bfloat16* base = pre + ((size_t)b * Ls + l) * C + c;
    const float4 wv = *(const float4*)(w + (size_t)c * 4);

    float v0 = (l >= 3) ? __bfloat162float(base[-3 * C]) : 0.f;
    float v1 = (l >= 2) ? __bfloat162float(base[-2 * C]) : 0.f;
    float v2 = (l >= 1) ? __bfloat162float(base[-1 * C]) : 0.f;
    float v3 = __bfloat162float(base[0]);
    float y = v0 * wv.x + v1 * wv.y + v2 * wv.z + v3 * wv.w;
    y = y / (1.f + expf(-y));   // SiLU

    if (do_norm) {
        float ss = y * y;
#pragma unroll
        for (int off = 32; off > 0; off >>= 1) ss += __shfl_xor(ss, off);
        if ((threadIdx.x & 63) == 0) red[threadIdx.x >> 6] = ss;
        __syncthreads();
        float tot = red[0] + red[1];
        y = y * rsqrtf(tot + 1e-6f) * scale;
    }
    out[((size_t)b * Ls + l) * C + c] = __float2bfloat16(y);
}

// ---------------------------------------------------------------------------
// beta = sigmoid(x@Wb), g = -exp(A_log)*softplus(x@Wgk+dt_bias).
// ---------------------------------------------------------------------------
__global__ void proj_small(const float* __restrict__ x, const float* __restrict__ Wb,
                           const float* __restrict__ Wgk, const float* __restrict__ A_log,
                           const float* __restrict__ dt_bias,
                           float* __restrict__ beta, float* __restrict__ g)
{
    const int row = blockIdx.x;
    const float* xr = x + (size_t)row * DHc;
    float accb[16], accg[16];
#pragma unroll
    for (int i = 0; i < 16; i++) { accb[i] = 0.f; accg[i] = 0.f; }

    for (int t = threadIdx.x; t < DHc; t += 64) {
        float xv = xr[t];
        const float* wb = Wb + (size_t)t * 16;
        const float* wg = Wgk + (size_t)t * 16;
#pragma unroll
        for (int hh = 0; hh < 16; hh++) {
            accb[hh] += xv * wb[hh];
            accg[hh] += xv * wg[hh];
        }
    }
#pragma unroll
    for (int hh = 0; hh < 16; hh++) {
        float vb = accb[hh], vg = accg[hh];
#pragma unroll
        for (int off = 32; off > 0; off >>= 1) {
            vb += __shfl_xor(vb, off);
            vg += __shfl_xor(vg, off);
        }
        if (threadIdx.x == 0) {
            beta[(size_t)row * 16 + hh] = 1.f / (1.f + expf(-vb));
            float z = vg + dt_bias[hh];
            float sp = (z > 20.f) ? z : log1pf(expf(z));
            g[(size_t)row * 16 + hh] = -expf(A_log[hh]) * sp;
        }
    }
}

// ---------------------------------------------------------------------------
// Per-chunk inclusive prefix sum of log-decay g. grid = BH*NCH blocks, 64 thr.
// ---------------------------------------------------------------------------
__global__ void bcum_kernel(const float* __restrict__ g, float* __restrict__ bcum)
{
    const int c = blockIdx.x & 15;
    const int bh = blockIdx.x >> 4;
    const int b = bh >> 4;
    const int h = bh & 15;
    const int t = threadIdx.x;
    float v = g[((size_t)(b * Ls + c * CC + t)) * 16 + h];
#pragma unroll
    for (int d = 1; d < 64; d <<= 1) {
        float n = __shfl_up(v, d, 64);
        if (t >= d) v += n;
    }
    bcum[(size_t)blockIdx.x * 64 + t] = v;
}

// ---------------------------------------------------------------------------
// Phase 1 (parallel over 1024 (b,h,chunk) tasks):
//   P = K K^T (MFMA); A[t][s] = beta_t exp(bc_t-bc_s) P (s<t);
//   forward-substitute (I+A)[U|Z] = [diag(beta)V | diag(beta)diag(exp(bc))K]
// ---------------------------------------------------------------------------
__launch_bounds__(256)
__global__ void gdn_phase1(const __hip_bfloat16* __restrict__ kc, const __hip_bfloat16* __restrict__ vc,
                           const float* __restrict__ bb, const float* __restrict__ bcum,
                           __hip_bfloat16* __restrict__ U, __hip_bfloat16* __restrict__ Z)
{
    const int task = blockIdx.x;
    const int c = task & 15;
    const int bh = task >> 4;
    const int b = bh >> 4;
    const int h = bh & 15;
    const int hk = h >> 2;
    const int tid = threadIdx.x;
    const int lane = tid & 63;
    const int wave = tid >> 6;
    const int q = lane >> 4;
    const int cL = lane & 15;

    __shared__ float Ab[64][68];
    __shared__ float sbeta[64], sbc[64];

    if (tid < 64) {
        sbeta[tid] = bb[((size_t)(b * Ls + c * CC + tid)) * 16 + h];
        sbc[tid] = bcum[((size_t)bh * 16 + c) * 64 + tid];
    }
    __syncthreads();

    const unsigned short* ku = (const unsigned short*)kc;
    const unsigned short* vu = (const unsigned short*)vc;

    // P = K K^T : wave w owns rows t in [16w,16w+16)
    f32x4 pacc[4];
#pragma unroll
    for (int j = 0; j < 4; j++) pacc[j] = (f32x4){0.f, 0.f, 0.f, 0.f};
    {
        const int t = 16 * wave + cL;
        const size_t krow = (((size_t)(b * Ls + c * CC + t)) * 4 + hk) * 128;
#pragma unroll
        for (int ks = 0; ks < 4; ks++) {
            bf16x8 af = *(const bf16x8*)&ku[krow + ks * 32 + q * 8];
#pragma unroll
            for (int j = 0; j < 4; j++) {
                const int s = 16 * j + cL;
                bf16x8 bf = *(const bf16x8*)&ku[(((size_t)(b * Ls + c * CC + s)) * 4 + hk) * 128 + ks * 32 + q * 8];
                pacc[j] = __builtin_amdgcn_mfma_f32_16x16x32_bf16(af, bf, pacc[j], 0, 0, 0);
            }
        }
    }
    // dump A (fp32, zero on/above diagonal)
#pragma unroll
    for (int j = 0; j < 4; j++)
#pragma unroll
        for (int p = 0; p < 4; p++) {
            const int t = 16 * wave + 4 * q + p;
            const int s = 16 * j + cL;
            float val = 0.f;
            if (s < t) val = sbeta[t] * __expf(sbc[t] - sbc[s]) * pacc[j][p];
            Ab[t][s] = val;
        }
    __syncthreads();

    // forward substitution, thread = one column of [U | Z]
    float u[64];
    const int j = tid;
    if (j < 128) {
#pragma unroll
        for (int t = 0; t < 64; t++)
            u[t] = sbeta[t] * b2f(vu[(((size_t)(b * Ls + c * CC + t)) * 4 + hk) * 128 + j]);
    } else {
        const int k = j - 128;
#pragma unroll
        for (int t = 0; t < 64; t++)
            u[t] = sbeta[t] * __expf(sbc[t]) * b2f(ku[(((size_t)(b * Ls + c * CC + t)) * 4 + hk) * 128 + k]);
    }
#pragma unroll
    for (int t = 1; t < 64; t++) {
        const float4* ar = (const float4*)Ab[t];
        const int nf = (t + 3) >> 2;
        float a0 = 0.f, a1 = 0.f, a2 = 0.f, a3 = 0.f;
#pragma unroll
        for (int i = 0; i < nf; i++) {
            float4 av = ar[i];
            a0 = fmaf(av.x, u[4 * i + 0], a0);
            a1 = fmaf(av.y, u[4 * i + 1], a1);
            a2 = fmaf(av.z, u[4 * i + 2], a2);
            a3 = fmaf(av.w, u[4 * i + 3], a3);
        }
        u[t] -= (a0 + a1) + (a2 + a3);
    }
    const size_t slab = ((size_t)bh * 16 + c) * 8192;
    if (j < 128) {
#pragma unroll
        for (int t = 0; t < 64; t++) U[slab + t * 128 + j] = __float2bfloat16(u[t]);
    } else {
#pragma unroll
        for (int t = 0; t < 64; t++) Z[slab + t * 128 + (j - 128)] = __float2bfloat16(u[t]);
    }
}

// ---------------------------------------------------------------------------
// Phase 2 v2: sequential over 16 chunks; 128 blocks = (b,h) x 2 v-halves.
// Block owns 64 v-columns of the state T[v][k] (v local, k=0..127) in regs:
//   per chunk: W = U - Z T^T ; O1 = (diag(E)Q) T^T ; T = eC T + W^T K_hat
// Pipelined: next chunk's K/U/Z/Q/bcum prefetched into registers.
// 3 barriers/chunk. W^T (bf16) stored over U buffer for phase 3.
// ---------------------------------------------------------------------------
__launch_bounds__(256, 1)
__global__ void gdn_phase2(const __hip_bfloat16* __restrict__ qc, const __hip_bfloat16* __restrict__ kc,
                           __hip_bfloat16* Uw /* in: U, out: W^T (aliased) */,
                           const __hip_bfloat16* __restrict__ Zbuf,
                           const float* __restrict__ bcum, float* __restrict__ Obuf)
{
    const int blk = blockIdx.x;
    const int half = blk & 1;
    const int bh = blk >> 1;
    const int b = bh >> 4;
    const int h = bh & 15;
    const int hk = h >> 2;
    const int vbase = half * 64;
    const int tid = threadIdx.x;
    const int lane = tid & 63;
    const int wave = tid >> 6;
    const int q = lane >> 4;
    const int cL = lane & 15;

    // LDS tiles (row strides are 16B multiples; <=2-way bank aliasing)
    __shared__ __align__(16) unsigned short Tb[64 * 136]; // T as B-frag: [vloc][k]
    __shared__ __align__(16) unsigned short Kt[128 * 72]; // K_hat^T: [k][tloc]
    __shared__ __align__(16) unsigned short Wt[64 * 72];  // W^T: [vloc][t]
    __shared__ __align__(16) unsigned short Us[64 * 72];  // U: [t][vloc]

    const unsigned short* qu = (const unsigned short*)qc;
    const unsigned short* ku = (const unsigned short*)kc;
    unsigned short* Uu = (unsigned short*)Uw;
    const unsigned short* Zu = (const unsigned short*)Zbuf;

    const int tloc = tid & 63;          // staging row (t for K, etc.)
    const int kg = tid >> 6;            // k-group for K staging
    const int trow = 16 * wave + cL;    // A-frag row (chunk-local t) for G1/G2

    // state accumulators: wave owns v in [16w,16w+16), Tacc[j] covers k in [16j,16j+16)
    f32x4 Tacc[8];
#pragma unroll
    for (int j = 0; j < 8; j++) Tacc[j] = (f32x4){0.f, 0.f, 0.f, 0.f};

    // ---- prefetch registers (chunk c+1 loaded during chunk c) ----
    bf16x8 Kreg[4], Zreg[4], Qreg[4];
    uint4 Ureg[2];
    float p_bctl, p_bctr, p_bc63;

    auto prefetch = [&](int c) {
        const size_t base_t = (size_t)b * Ls + (size_t)c * CC;
        const size_t slab = ((size_t)bh * 16 + c) * 8192;
        const size_t krow = ((base_t + tloc) * 4 + hk) * 128 + 32 * kg;
#pragma unroll
        for (int m = 0; m < 4; m++) Kreg[m] = *(const bf16x8*)&ku[krow + m * 8];
#pragma unroll
        for (int i = 0; i < 2; i++) {
            const int g = 2 * tid + i;
            Ureg[i] = *(const uint4*)&Uu[slab + (size_t)(g >> 3) * 128 + vbase + (g & 7) * 8];
        }
        const size_t zrow = slab + (size_t)trow * 128;
        const size_t qrow = ((base_t + trow) * 16 + h) * 128;
#pragma unroll
        for (int ks = 0; ks < 4; ks++) {
            Zreg[ks] = *(const bf16x8*)&Zu[zrow + ks * 32 + q * 8];
            Qreg[ks] = *(const bf16x8*)&qu[qrow + ks * 32 + q * 8];
        }
        const float* bc = bcum + ((size_t)bh * 16 + c) * 64;
        p_bctl = bc[tloc];
        p_bctr = bc[trow];
        p_bc63 = bc[63];
    };

    prefetch(0);

    for (int c = 0; c < NCH; ++c) {
        // consume prefetched values into locals
        bf16x8 kr[4], zr[4], qr[4];
        uint4 ur[2];
#pragma unroll
        for (int m = 0; m < 4; m++) { kr[m] = Kreg[m]; zr[m] = Zreg[m]; qr[m] = Qreg[m]; }
        ur[0] = Ureg[0]; ur[1] = Ureg[1];
        const float bctl = p_bctl, bctr = p_bctr, bc63 = p_bc63;
        const size_t slab = ((size_t)bh * 16 + c) * 8192;

        // issue next chunk's global loads now (land during this chunk's compute)
        if (c + 1 < NCH) prefetch(c + 1);

        const float ek = __expf(bc63 - bctl);   // K_hat row scale (my tloc)
        const float Et = __expf(bctr);          // q row scale (my trow)
        const float eC = __expf(bc63);          // full-chunk decay

        __syncthreads();  // barrier 1: prev chunk readers of Tb/Kt/Us/Wt done

        // stage K_hat^T: rows k=32kg+8m+e, col tloc
#pragma unroll
        for (int m = 0; m < 4; m++) {
            union { bf16x8 v; unsigned short us[8]; } kv;
            kv.v = scale_frag(kr[m], ek);
#pragma unroll
            for (int e = 0; e < 8; e++) Kt[(32 * kg + 8 * m + e) * 72 + tloc] = kv.us[e];
        }
        // stage U: [t][vloc]
#pragma unroll
        for (int i = 0; i < 2; i++) {
            const int g = 2 * tid + i;
            *(uint4*)&Us[(g >> 3) * 72 + (g & 7) * 8] = ur[i];
        }
        // dump T into Tb: row v=16w+4q+p, col k=16j+cL
#pragma unroll
        for (int j = 0; j < 8; j++)
#pragma unroll
            for (int p = 0; p < 4; p++)
                Tb[(16 * wave + 4 * q + p) * 136 + 16 * j + cL] = f2b(Tacc[j][p]);

        __syncthreads();  // barrier 2: staging visible

        // G1: W' = Z T^T ; G2: O1 = (Et q) T^T   (output [t][v], 16x16 tiles)
        f32x4 Wacc[4], Oacc[4];
#pragma unroll
        for (int j = 0; j < 4; j++) { Wacc[j] = (f32x4){0.f,0.f,0.f,0.f}; Oacc[j] = (f32x4){0.f,0.f,0.f,0.f}; }
#pragma unroll
        for (int ks = 0; ks < 4; ks++) {
            bf16x8 aq = scale_frag(qr[ks], Et);
#pragma unroll
            for (int j = 0; j < 4; j++) {
                bf16x8 bt = *(const bf16x8*)&Tb[(16 * j + cL) * 136 + 32 * ks + 8 * q];
                Wacc[j] = __builtin_amdgcn_mfma_f32_16x16x32_bf16(zr[ks], bt, Wacc[j], 0, 0, 0);
                Oacc[j] = __builtin_amdgcn_mfma_f32_16x16x32_bf16(aq, bt, Oacc[j], 0, 0, 0);
            }
        }
        // epilogue: W = U - W'; dump W^T; store O1 (fp32, fire-and-forget)
#pragma unroll
        for (int j = 0; j < 4; j++)
#pragma unroll
            for (int p = 0; p < 4; p++) {
                const int t = 16 * wave + 4 * q + p;
                const int v = 16 * j + cL;
                const float w = b2f(Us[t * 72 + v]) - Wacc[j][p];
                Wt[v * 72 + t] = f2b(w);
                Obuf[((size_t)b * Ls + c * CC + t) * 2048 + h * 128 + vbase + v] = Oacc[j][p];
            }

        __syncthreads();  // barrier 3: Wt complete

        // store W^T to global over U slab (phase 3 layout: [vglobal][t], stride 64)
        {
            const int vloc = tid >> 2, part = tid & 3;
            const size_t dst = slab + (size_t)(vbase + vloc) * 64 + part * 16;
            *(uint4*)&Uu[dst]     = *(const uint4*)&Wt[vloc * 72 + part * 16];
            *(uint4*)&Uu[dst + 8] = *(const uint4*)&Wt[vloc * 72 + part * 16 + 8];
        }
        // G3: T = eC*T + W^T K_hat  (output [v][k])
#pragma unroll
        for (int j = 0; j < 8; j++)
#pragma unroll
            for (int p = 0; p < 4; p++) Tacc[j][p] *= eC;
#pragma unroll
        for (int ks = 0; ks < 2; ks++) {
            bf16x8 aw = *(const bf16x8*)&Wt[(16 * wave + cL) * 72 + 32 * ks + 8 * q];
#pragma unroll
            for (int j = 0; j < 8; j++) {
                bf16x8 bk = *(const bf16x8*)&Kt[(16 * j + cL) * 72 + 32 * ks + 8 * q];
                Tacc[j] = __builtin_amdgcn_mfma_f32_16x16x32_bf16(aw, bk, Tacc[j], 0, 0, 0);
            }
        }
    }
}

// ---------------------------------------------------------------------------
// Phase 3 (parallel over 1024 (b,h,chunk) tasks):
//   M[t][s] = exp(bc_t-bc_s) (q_t.k_s), s<=t;  O += M W  (W^T read from Uw)
// ---------------------------------------------------------------------------
__launch_bounds__(256)
__global__ void gdn_phase3(const __hip_bfloat16* __restrict__ qc, const __hip_bfloat16* __restrict__ kc,
                           const __hip_bfloat16* __restrict__ WT, const float* __restrict__ bcum,
                           float* __restrict__ Obuf)
{
    const int task = blockIdx.x;
    const int c = task & 15;
    const int bh = task >> 4;
    const int b = bh >> 4;
    const int h = bh & 15;
    const int hk = h >> 2;
    const int tid = threadIdx.x;
    const int lane = tid & 63;
    const int wave = tid >> 6;
    const int q = lane >> 4;
    const int cL = lane & 15;

    __shared__ __align__(16) unsigned short Mb[64 * 72];
    __shared__ float sbc[64];

    if (tid < 64) sbc[tid] = bcum[((size_t)bh * 16 + c) * 64 + tid];
    __syncthreads();

    const unsigned short* qu = (const unsigned short*)qc;
    const unsigned short* ku = (const unsigned short*)kc;
    const unsigned short* wu = (const unsigned short*)WT;

    // Pq = Q K^T
    f32x4 pacc[4];
#pragma unroll
    for (int j = 0; j < 4; j++) pacc[j] = (f32x4){0.f, 0.f, 0.f, 0.f};
    {
        const int t = 16 * wave + cL;
        const size_t qrow = (((size_t)(b * Ls + c * CC + t)) * 16 + h) * 128;
#pragma unroll
        for (int ks = 0; ks < 4; ks++) {
            bf16x8 aq = *(const bf16x8*)&qu[qrow + ks * 32 + q * 8];
#pragma unroll
            for (int j = 0; j < 4; j++) {
                const int s = 16 * j + cL;
                bf16x8 bk = *(const bf16x8*)&ku[(((size_t)(b * Ls + c * CC + s)) * 4 + hk) * 128 + ks * 32 + q * 8];
                pacc[j] = __builtin_amdgcn_mfma_f32_16x16x32_bf16(aq, bk, pacc[j], 0, 0, 0);
            }
        }
    }
#pragma unroll
    for (int j = 0; j < 4; j++)
#pragma unroll
        for (int p = 0; p < 4; p++) {
            const int t = 16 * wave + 4 * q + p;
            const int s = 16 * j + cL;
            const float val = (s <= t) ? __expf(sbc[t] - sbc[s]) * pacc[j][p] : 0.f;
            Mb[t * 72 + s] = f2b(val);
        }
    __syncthreads();

    // O2 = M W ; B-frags from W^T (global, contiguous)
    f32x4 oacc[8];
#pragma unroll
    for (int j = 0; j < 8; j++) oacc[j] = (f32x4){0.f, 0.f, 0.f, 0.f};
    const size_t slab = ((size_t)bh * 16 + c) * 8192;
#pragma unroll
    for (int ks = 0; ks < 2; ks++) {
        bf16x8 am = *(const bf16x8*)&Mb[(16 * wave + cL) * 72 + ks * 32 + q * 8];
#pragma unroll
        for (int j = 0; j < 8; j++) {
            const int v = 16 * j + cL;
            bf16x8 bw = *(const bf16x8*)&wu[slab + (size_t)v * 64 + ks * 32 + q * 8];
            oacc[j] = __builtin_amdgcn_mfma_f32_16x16x32_bf16(am, bw, oacc[j], 0, 0, 0);
        }
    }
#pragma unroll
    for (int j = 0; j < 8; j++)
#pragma unroll
        for (int p = 0; p < 4; p++) {
            const int t = 16 * wave + 4 * q + p;
            const int v = 16 * j + cL;
            const size_t a = ((size_t)(b * Ls + c * CC + t)) * 2048 + h * 128 + v;
            Obuf[a] += oacc[j][p];
        }
}

// ---------------------------------------------------------------------------
// FusedRMSNormGated: reads fp32 o, bf16 gate; writes bf16 normalized o.
// ---------------------------------------------------------------------------
__global__ void gated_rmsnorm(const float* __restrict__ o, const __hip_bfloat16* __restrict__ gate,
                              const float* __restrict__ w, __hip_bfloat16* __restrict__ out)
{
    const size_t row = blockIdx.x;
    const float* op = o + row * Dh;
    const __hip_bfloat16* gp = gate + row * Dh;
    const int t = threadIdx.x;
    float o0 = op[t], o1 = op[t + 64];
    float ss = o0 * o0 + o1 * o1;
#pragma unroll
    for (int off = 32; off > 0; off >>= 1) ss += __shfl_xor(ss, off);
    float r = rsqrtf(ss * (1.f / 128.f) + 1e-5f);
    float g0 = __bfloat162float(gp[t]), g1 = __bfloat162float(gp[t + 64]);
    out[row * Dh + t]      = __float2bfloat16(o0 * r * w[t]      * (g0 / (1.f + expf(-g0))));
    out[row * Dh + t + 64] = __float2bfloat16(o1 * r * w[t + 64] * (g1 / (1.f + expf(-g1))));
}

// ---------------------------------------------------------------------------
extern "C" void kernel_launch(void* const* d_in, const int* in_sizes, int n_in,
                              void* d_out, int out_size, void* d_ws, size_t ws_size,
                              hipStream_t stream)
{
    const float* x     = (const float*)d_in[0];
    const float* Wq    = (const float*)d_in[1];
    const float* Wk    = (const float*)d_in[2];
    const float* Wv    = (const float*)d_in[3];
    const float* Wb    = (const float*)d_in[4];
    const float* Wgk   = (const float*)d_in[5];
    const float* A_log = (const float*)d_in[6];
    const float* dtb   = (const float*)d_in[7];
    const float* cq    = (const float*)d_in[8];
    const float* ck    = (const float*)d_in[9];
    const float* cv    = (const float*)d_in[10];
    const float* Wg    = (const float*)d_in[11];
    const float* onw   = (const float*)d_in[12];
    const float* Wo    = (const float*)d_in[13];

    // --- workspace layout (bytes), total 75,759,616 B ---
    char* wsb = (char*)d_ws;
    __hip_bfloat16* xbf  = (__hip_bfloat16*)(wsb + 0);          // [4096,2048]   16.78 MB
    __hip_bfloat16* qcb  = (__hip_bfloat16*)(wsb + 16777216);   // [4096,16,128] 16.78 MB
    __hip_bfloat16* kcb  = (__hip_bfloat16*)(wsb + 33554432);   // [4096,4,128]   4.19 MB
    __hip_bfloat16* vcb  = (__hip_bfloat16*)(wsb + 37748736);   // [4096,4,128]   4.19 MB
    __hip_bfloat16* Uw   = (__hip_bfloat16*)(wsb + 41943040);   // U then W^T    16.78 MB
    __hip_bfloat16* Zb   = (__hip_bfloat16*)(wsb + 58720256);   // Z then gate   16.78 MB
    float*          bcum = (float*)(wsb + 75497472);            // [64,16,64]     0.26 MB

    // --- d_out doubles as early scratch (dead before phase 2 writes O) ---
    char* dob = (char*)d_out;
    __hip_bfloat16* pre = (__hip_bfloat16*)dob;                 // conv pre-acts (<=16.78 MB)
    __hip_bfloat16* BT  = (__hip_bfloat16*)(dob + 16777216);    // weight transposes (<=8.39 MB)
    float* bb = (float*)(dob + 25165824);                       // beta [4096,16]
    float* gb = (float*)(dob + 25427968);                       // g    [4096,16]
    float* Obuf = (float*)d_out;                                // fp32 O [4096,2048]

    const float qscale = 0.08838834764831845f; // D^-0.5
    const int nx = Mrows * DHc;

    f32_to_bf16<<<nx / 4 / 256, 256, 0, stream>>>(x, xbf, nx);
    proj_small<<<Mrows, 64, 0, stream>>>(x, Wb, Wgk, A_log, dtb, bb, gb);
    bcum_kernel<<<64 * NCH, 64, 0, stream>>>(gb, bcum);

    // q
    transpose_to_bf16<<<dim3(32, 32), 256, 0, stream>>>(Wq, BT, 2048, 2048);
    gemm_bt_bf16<<<dim3(16, 32), 256, 0, stream>>>(xbf, BT, pre, 2048, 2048, 1);
    conv_silu_norm<<<Mrows * HQc, 128, 0, stream>>>(pre, cq, qcb, HQc, 1, qscale);
    // k
    transpose_to_bf16<<<dim3(8, 32), 256, 0, stream>>>(Wk, BT, 2048, 512);
    gemm_bt_bf16<<<dim3(4, 32), 256, 0, stream>>>(xbf, BT, pre, 512, 2048, 1);
    conv_silu_norm<<<Mrows * HKc, 128, 0, stream>>>(pre, ck, kcb, HKc, 1, 1.0f);
    // v
    transpose_to_bf16<<<dim3(8, 32), 256, 0, stream>>>(Wv, BT, 2048, 512);
    gemm_bt_bf16<<<dim3(4, 32), 256, 0, stream>>>(xbf, BT, pre, 512, 2048, 1);
    conv_silu_norm<<<Mrows * HKc, 128, 0, stream>>>(pre, cv, vcb, HKc, 0, 1.0f);

    // chunked delta-rule
    gdn_phase1<<<64 * NCH, 256, 0, stream>>>(kcb, vcb, bb, bcum, Uw, Zb);
    gdn_phase2<<<128, 256, 0, stream>>>(qcb, kcb, Uw, Zb, bcum, Obuf);
    gdn_phase3<<<64 * NCH, 256, 0, stream>>>(qcb, kcb, Uw, bcum, Obuf);

    // gate projection (into Zb; Z dead after phase 2), rmsnorm, output proj
    transpose_to_bf16<<<dim3(32, 32), 256, 0, stream>>>(Wg, (__hip_bfloat16*)Uw, 2048, 2048); // Uw dead after phase 3
    gemm_bt_bf16<<<dim3(16, 32), 256, 0, stream>>>(xbf, (__hip_bfloat16*)Uw, Zb, 2048, 2048, 1);
    gated_rmsnorm<<<Mrows * Hc, 64, 0, stream>>>(Obuf, Zb, onw, qcb); // qcb dead after phase 3
    transpose_to_bf16<<<dim3(32, 32), 256, 0, stream>>>(Wo, (__hip_bfloat16*)Uw, 2048, 2048);
    gemm_bt_bf16<<<dim3(16, 32), 256, 0, stream>>>(qcb, (__hip_bfloat16*)Uw, d_out, 2048, 2048, 0);
}